// Round 1
// 3088.710 us; speedup vs baseline: 1.6819x; 1.6819x over previous
//
#include <hip/hip_runtime.h>
#include <cstdio>

// ============================================================================
// ROUND 15: flash-style attention rewrite.
// R14 counters: attention_f32 = 2700us (52% of total), VALUBusy 19.6%, HBM
// 0.4%, MfmaUtil 0, bank-conflicts 0 -> latency/reuse-bound, not any pipe.
// Old kernel: 1 query per block => every block streams 2MB K+V from L2
// (32 GB L2 traffic, 0.5 FLOP/byte). Total attn math is only 17.2 GFLOP
// (110us at fp32 VALU peak).
// New: 64 queries/block, K/V staged 64-m tiles through LDS, online softmax
// in registers, 4n x 4m register tile per thread (16 FMA per 2 ds_read_b128),
// issue-early global loads for tile t+1 (T14), XCD-aware block->batch decode
// so each XCD's L2 holds one batch's 2MB K+V.
// Convs unchanged this round (they are the next target).
// ============================================================================

// Keeps the harness-stub identifier name (unused utility).
__global__ __launch_bounds__(256) void CrossModalityPositionAttention_56556129354448_kernel(
    float* dst, float val, int n)
{
  const int i = blockIdx.x * 256 + threadIdx.x;
  if (i < n) dst[i] = val;
}

// ---------------------------------------------------------------------------
// Conv3x3(pad=1) + folded BN + ReLU.  Cin=256 -> Cout=64.  All fp32.
// in: NCHW [4][256][64][64].  out: [4][64][4096] (NCHW).
// grid (16, 64, 4): x = y-row group (4 rows), y = co, z = b.  block 256.
__global__ __launch_bounds__(256) void conv1_f32(
    const float* __restrict__ in, const float* __restrict__ w,
    const float* __restrict__ bi, const float* __restrict__ g,
    const float* __restrict__ be, const float* __restrict__ mu,
    const float* __restrict__ va, float* __restrict__ out)
{
  const int b = blockIdx.z;
  const int co = blockIdx.y;
  const int y = blockIdx.x * 4 + (threadIdx.x >> 6);
  const int x = threadIdx.x & 63;

  float acc = 0.f;
  const float* inb = in + (size_t)(b * 256) * 4096;
  const float* wco = w + (size_t)co * 256 * 9;
  for (int ci = 0; ci < 256; ++ci) {
    const float* ip = inb + (size_t)ci * 4096;
    const float* wp = wco + ci * 9;
    #pragma unroll
    for (int ky = 0; ky < 3; ++ky) {
      const int yy = y + ky - 1;
      if (yy < 0 || yy > 63) continue;
      #pragma unroll
      for (int kx = 0; kx < 3; ++kx) {
        const int xx = x + kx - 1;
        if (xx < 0 || xx > 63) continue;
        acc += ip[yy * 64 + xx] * wp[ky * 3 + kx];
      }
    }
  }
  const float inv = g[co] * rsqrtf(va[co] + 1e-5f);
  float r = (acc + bi[co]) * inv + be[co] - mu[co] * inv;
  r = fmaxf(r, 0.f);
  out[((size_t)b * 64 + co) * 4096 + y * 64 + x] = r;
}

// ---------------------------------------------------------------------------
// Flash-style attention, fp32. q,k,v,f are [4][64][4096] (c-major rows).
// Grid: 256 blocks x 256 threads. Block handles 64 queries (one batch).
// Block decode: b = (lin&7)>>1, nb = (lin>>3)*2 | (lin&1)  (bijective; keeps
// each XCD (lin%8) on a single batch => K+V working set 2MB < 4MB L2/XCD).
// Thread (ng = t>>4, mg = t&15) owns a 4n x 4m score tile (QK phase) and a
// 4n x 4c output tile (PV phase, c-group = mg). Softmax state replicated
// across the 16 mg-lanes of each ng via __shfl_xor (masks 1,2,4,8).
// LDS: K tile [c][m] (reused as P [n][m]), V tile transposed [m][c], Q [c][n],
// all stride 68 floats (16B-aligned, conflict-free patterns).
__global__ __launch_bounds__(256) void attention_flash_f32(
    const float* __restrict__ q, const float* __restrict__ k,
    const float* __restrict__ v, float* __restrict__ f)
{
  __shared__ float kp_lds[64 * 68];  // K tile [c][m] -> reused as P [n][m]
  __shared__ float vt_lds[64 * 68];  // V tile transposed [m][c]
  __shared__ float qt_lds[64 * 68];  // Q tile [c][n] -> reused for epilogue

  const int lin = blockIdx.x;
  const int b = (lin & 7) >> 1;
  const int nb = ((lin >> 3) << 1) | (lin & 1);
  const int n0 = nb * 64;

  const int t = threadIdx.x;
  const int mg = t & 15;   // m-group (QK) == c-group (PV)
  const int ng = t >> 4;   // n-group

  const float* qb = q + (size_t)b * 64 * 4096;
  const float* kb = k + (size_t)b * 64 * 4096;
  const float* vb = v + (size_t)b * 64 * 4096;

  // ---- stage Q tile [c][n0..n0+63] into qt_lds[c][n] (coalesced 256B rows)
  {
    const int nn = t & 15;   // float4 index within row
    const int c0 = t >> 4;
    #pragma unroll
    for (int p = 0; p < 4; ++p) {
      const int c = c0 + p * 16;
      const float4 val = *(const float4*)(qb + (size_t)c * 4096 + n0 + nn * 4);
      *(float4*)(qt_lds + c * 68 + nn * 4) = val;
    }
  }

  float acc[4][4] = {{0.f}};   // O[n_i][c_j]
  float m_run[4], l_run[4];
  #pragma unroll
  for (int i = 0; i < 4; ++i) { m_run[i] = -1e30f; l_run[i] = 0.f; }

  // staging thread mappings
  const int kc  = t >> 2;   // K row (c)
  const int kf  = t & 3;    // K float4 base index
  const int vm4 = t & 15;   // V float4 (m) index
  const int vc0 = t >> 4;   // V row (c) base, passes += 16

  float4 kreg[4], vreg[4];
  // preload tile 0 into regs
  #pragma unroll
  for (int r = 0; r < 4; ++r)
    kreg[r] = *(const float4*)(kb + (size_t)kc * 4096 + (kf + 4 * r) * 4);
  #pragma unroll
  for (int p = 0; p < 4; ++p)
    vreg[p] = *(const float4*)(vb + (size_t)(vc0 + 16 * p) * 4096 + vm4 * 4);

  for (int tile = 0; tile < 64; ++tile) {
    __syncthreads();  // prior tile's P/V reads done (and Q staged on iter 0)

    // write staged regs -> LDS
    #pragma unroll
    for (int r = 0; r < 4; ++r)
      *(float4*)(kp_lds + kc * 68 + (kf + 4 * r) * 4) = kreg[r];
    #pragma unroll
    for (int p = 0; p < 4; ++p) {
      const float4 vv = vreg[p];
      const int c = vc0 + 16 * p;
      vt_lds[(vm4 * 4 + 0) * 68 + c] = vv.x;
      vt_lds[(vm4 * 4 + 1) * 68 + c] = vv.y;
      vt_lds[(vm4 * 4 + 2) * 68 + c] = vv.z;
      vt_lds[(vm4 * 4 + 3) * 68 + c] = vv.w;
    }
    // issue next-tile global loads early (hide L2 latency under compute)
    if (tile < 63) {
      const int m0 = (tile + 1) * 64;
      #pragma unroll
      for (int r = 0; r < 4; ++r)
        kreg[r] = *(const float4*)(kb + (size_t)kc * 4096 + m0 + (kf + 4 * r) * 4);
      #pragma unroll
      for (int p = 0; p < 4; ++p)
        vreg[p] = *(const float4*)(vb + (size_t)(vc0 + 16 * p) * 4096 + m0 + vm4 * 4);
    }
    __syncthreads();  // LDS tiles ready

    // ---- QK: s[i][j] = sum_c Q[c][4ng+i] * K[c][4mg+j]
    float s[4][4] = {{0.f}};
    #pragma unroll 8
    for (int c = 0; c < 64; ++c) {
      const float4 q4 = *(const float4*)(qt_lds + c * 68 + 4 * ng);
      const float4 k4 = *(const float4*)(kp_lds + c * 68 + 4 * mg);
      const float qa[4] = {q4.x, q4.y, q4.z, q4.w};
      const float ka[4] = {k4.x, k4.y, k4.z, k4.w};
      #pragma unroll
      for (int i = 0; i < 4; ++i)
        #pragma unroll
        for (int j = 0; j < 4; ++j)
          s[i][j] += qa[i] * ka[j];
    }

    // ---- online softmax (per n-row, across 16 mg-lanes)
    #pragma unroll
    for (int i = 0; i < 4; ++i) {
      float rm = fmaxf(fmaxf(s[i][0], s[i][1]), fmaxf(s[i][2], s[i][3]));
      rm = fmaxf(rm, __shfl_xor(rm, 1));
      rm = fmaxf(rm, __shfl_xor(rm, 2));
      rm = fmaxf(rm, __shfl_xor(rm, 4));
      rm = fmaxf(rm, __shfl_xor(rm, 8));
      const float mn = fmaxf(m_run[i], rm);
      const float al = __expf(m_run[i] - mn);
      m_run[i] = mn;
      float rs = 0.f;
      #pragma unroll
      for (int j = 0; j < 4; ++j) { s[i][j] = __expf(s[i][j] - mn); rs += s[i][j]; }
      rs += __shfl_xor(rs, 1);
      rs += __shfl_xor(rs, 2);
      rs += __shfl_xor(rs, 4);
      rs += __shfl_xor(rs, 8);
      l_run[i] = al * l_run[i] + rs;
      #pragma unroll
      for (int j = 0; j < 4; ++j) acc[i][j] *= al;
    }

    __syncthreads();  // all K reads done before P overwrites kp_lds
    #pragma unroll
    for (int i = 0; i < 4; ++i)
      *(float4*)(kp_lds + (4 * ng + i) * 68 + 4 * mg) =
          make_float4(s[i][0], s[i][1], s[i][2], s[i][3]);
    __syncthreads();

    // ---- PV: acc[i][j] += sum_m P[4ng+i][m] * V[4mg+j][m]
    #pragma unroll 4
    for (int m4 = 0; m4 < 16; ++m4) {
      float pa[4][4], va[4][4];
      #pragma unroll
      for (int i = 0; i < 4; ++i) {
        const float4 p4 = *(const float4*)(kp_lds + (4 * ng + i) * 68 + m4 * 4);
        pa[i][0] = p4.x; pa[i][1] = p4.y; pa[i][2] = p4.z; pa[i][3] = p4.w;
      }
      #pragma unroll
      for (int jm = 0; jm < 4; ++jm) {
        const float4 v4 = *(const float4*)(vt_lds + (m4 * 4 + jm) * 68 + 4 * mg);
        va[jm][0] = v4.x; va[jm][1] = v4.y; va[jm][2] = v4.z; va[jm][3] = v4.w;
      }
      #pragma unroll
      for (int i = 0; i < 4; ++i)
        #pragma unroll
        for (int jm = 0; jm < 4; ++jm)
          #pragma unroll
          for (int j = 0; j < 4; ++j)
            acc[i][j] += pa[i][jm] * va[jm][j];
    }
  }

  // ---- epilogue: normalize, transpose through LDS (qt free), coalesced store
  __syncthreads();
  #pragma unroll
  for (int i = 0; i < 4; ++i) {
    const float inv = 1.f / l_run[i];
    #pragma unroll
    for (int j = 0; j < 4; ++j)
      qt_lds[(4 * mg + j) * 68 + 4 * ng + i] = acc[i][j] * inv;  // [c][n]
  }
  __syncthreads();
  {
    const int c = t >> 2;
    #pragma unroll
    for (int r = 0; r < 4; ++r) {
      const int f4i = (t & 3) + 4 * r;
      *(float4*)(f + ((size_t)b * 64 + c) * 4096 + n0 + f4i * 4) =
          *(const float4*)(qt_lds + c * 68 + f4i * 4);
    }
  }
}

// ---------------------------------------------------------------------------
// Conv3x3(pad=1) + folded BN + ReLU + residual.  Cin=64 -> Cout=256.  fp32.
// fin: [4][64][4096].  res/out: NCHW [4][256][64][64].
// grid (16, 256, 4): x = y-row group, y = co, z = b.  block 256.
__global__ __launch_bounds__(256) void conv_r_f32(
    const float* __restrict__ fin, const float* __restrict__ w,
    const float* __restrict__ bi, const float* __restrict__ g,
    const float* __restrict__ be, const float* __restrict__ mu,
    const float* __restrict__ va, const float* __restrict__ res,
    float* __restrict__ out)
{
  const int b = blockIdx.z;
  const int co = blockIdx.y;
  const int y = blockIdx.x * 4 + (threadIdx.x >> 6);
  const int x = threadIdx.x & 63;

  float acc = 0.f;
  const float* inb = fin + (size_t)(b * 64) * 4096;
  const float* wco = w + (size_t)co * 64 * 9;
  for (int ci = 0; ci < 64; ++ci) {
    const float* ip = inb + (size_t)ci * 4096;
    const float* wp = wco + ci * 9;
    #pragma unroll
    for (int ky = 0; ky < 3; ++ky) {
      const int yy = y + ky - 1;
      if (yy < 0 || yy > 63) continue;
      #pragma unroll
      for (int kx = 0; kx < 3; ++kx) {
        const int xx = x + kx - 1;
        if (xx < 0 || xx > 63) continue;
        acc += ip[yy * 64 + xx] * wp[ky * 3 + kx];
      }
    }
  }
  const float inv = g[co] * rsqrtf(va[co] + 1e-5f);
  float r = (acc + bi[co]) * inv + be[co] - mu[co] * inv;
  r = fmaxf(r, 0.f);
  const size_t idx = ((size_t)b * 256 + co) * 4096 + y * 64 + x;
  out[idx] = res[idx] + r;
}

// ---------------------------------------------------------------------------
extern "C" void kernel_launch(void* const* d_in, const int* in_sizes, int n_in,
                              void* d_out, int out_size, void* d_ws, size_t ws_size,
                              hipStream_t stream) {
  const float* f1 = (const float*)d_in[0];
  const float* f2 = (const float*)d_in[1];
  const float* qw = (const float*)d_in[2];  const float* qb = (const float*)d_in[3];
  const float* qg = (const float*)d_in[4];  const float* qbe = (const float*)d_in[5];
  const float* qm = (const float*)d_in[6];  const float* qv = (const float*)d_in[7];
  const float* kw = (const float*)d_in[8];  const float* kb = (const float*)d_in[9];
  const float* kg = (const float*)d_in[10]; const float* kbe = (const float*)d_in[11];
  const float* km = (const float*)d_in[12]; const float* kv = (const float*)d_in[13];
  const float* vw = (const float*)d_in[14]; const float* vb = (const float*)d_in[15];
  const float* vg = (const float*)d_in[16]; const float* vbe = (const float*)d_in[17];
  const float* vm = (const float*)d_in[18]; const float* vv = (const float*)d_in[19];
  const float* rw = (const float*)d_in[20]; const float* rb = (const float*)d_in[21];
  const float* rg = (const float*)d_in[22]; const float* rbe = (const float*)d_in[23];
  const float* rm = (const float*)d_in[24]; const float* rv = (const float*)d_in[25];

  hipStreamCaptureStatus cap = hipStreamCaptureStatusNone;
  unsigned long long capid = 0;
  const hipError_t ce = hipStreamGetCaptureInfo(stream, &cap, &capid);
  const bool capturing = (ce == hipSuccess) && (cap != hipStreamCaptureStatusNone);

  // Workspace: q,k,v,f fp32 [4][64][4096] = 4 MB each (ws_size = 256 MB).
  const size_t SZ1 = (size_t)4 * 64 * 4096 * 4;
  float* qp = (float*)d_ws;
  float* kp = (float*)((char*)d_ws + SZ1);
  float* vp = (float*)((char*)d_ws + 2 * SZ1);
  float* fp = (float*)((char*)d_ws + 3 * SZ1);

  conv1_f32<<<dim3(16, 64, 4), 256, 0, stream>>>(f2, qw, qb, qg, qbe, qm, qv, qp);
  conv1_f32<<<dim3(16, 64, 4), 256, 0, stream>>>(f1, kw, kb, kg, kbe, km, kv, kp);
  conv1_f32<<<dim3(16, 64, 4), 256, 0, stream>>>(f1, vw, vb, vg, vbe, vm, vv, vp);
  attention_flash_f32<<<dim3(256), 256, 0, stream>>>(qp, kp, vp, fp);
  conv_r_f32<<<dim3(16, 256, 4), 256, 0, stream>>>(fp, rw, rb, rg, rbe, rm, rv,
                                                   f1, (float*)d_out);

  if (!capturing) {
    const hipError_t le = hipGetLastError();
    const hipError_t se = hipStreamSynchronize(stream);
    float h[4] = {0, 0, 0, 0};
    (void)hipMemcpy(h, d_out, 16, hipMemcpyDeviceToHost);
    fprintf(stderr,
        "ATHENA_R15 flash-attn le=%d sync=%d out=[%g %g %g %g]\n",
        (int)le, (int)se, h[0], h[1], h[2], h[3]);
    fflush(stderr);
  }
}

// Round 3
// 1446.244 us; speedup vs baseline: 3.5920x; 2.1357x over previous
//
#include <hip/hip_runtime.h>
#include <cstdio>

// ============================================================================
// ROUND 17 = ROUND 16 retry (bench infra failed twice; no kernel verdict).
// R16 theory: conv1_f32 x3 = 2.48ms of 3.09ms, VALUBusy 12%, VGPR=8 ->
// serial 1-output/thread chain. Fix: fused q+k+v conv (k,v share input f1),
// register tile 4co x 4px x 3 tensors, LDS-staged input, issue-early loads.
// conv_r same structure. Flash attention unchanged (R15, verified).
// ============================================================================

// Keeps the harness-stub identifier name (unused utility).
__global__ __launch_bounds__(256) void CrossModalityPositionAttention_56556129354448_kernel(
    float* dst, float val, int n)
{
  const int i = blockIdx.x * 256 + threadIdx.x;
  if (i < n) dst[i] = val;
}

// ---------------------------------------------------------------------------
// Fused q/k/v conv3x3 + BN + ReLU.  q = conv(f2), k = conv(f1), v = conv(f1).
// Cin=256 -> Cout=64 each.  In: NCHW [4][256][64][64] fp32.
// Out: three [4][64][4096] fp32.
// grid (4, 16, 4): x = 16-row group, y = co-group (4 couts), z = b. block 256.
// Thread (ry = t>>4, xg = t&15): 4 px in x, 4 couts, for q,k,v -> 48 accs.
// LDS: two tiles (f1, f2) x 2 ci x [18 rows][64 cols] + 8-float head/tail pad.
#define TROWS 18
#define TSTR  64
#define TPAD  8
#define TSZ   (TPAD + TROWS * TSTR + TPAD)   // 1168 floats

__global__ __launch_bounds__(256, 1) void convqkv_f32(
    const float* __restrict__ f1, const float* __restrict__ f2,
    const float* __restrict__ q_w, const float* __restrict__ q_b,
    const float* __restrict__ q_g, const float* __restrict__ q_be,
    const float* __restrict__ q_m, const float* __restrict__ q_va,
    const float* __restrict__ k_w, const float* __restrict__ k_b,
    const float* __restrict__ k_g, const float* __restrict__ k_be,
    const float* __restrict__ k_m, const float* __restrict__ k_va,
    const float* __restrict__ v_w, const float* __restrict__ v_b,
    const float* __restrict__ v_g, const float* __restrict__ v_be,
    const float* __restrict__ v_m, const float* __restrict__ v_va,
    float* __restrict__ qo, float* __restrict__ ko, float* __restrict__ vo)
{
  __shared__ float tA[2][TSZ];  // f1 tiles (ci 2r, 2r+1)
  __shared__ float tB[2][TSZ];  // f2 tiles

  const int b   = blockIdx.z;
  const int co0 = blockIdx.y * 4;
  const int y0  = blockIdx.x * 16;
  const int t   = threadIdx.x;
  const int ry  = t >> 4;       // output row within tile (0..15)
  const int xg  = t & 15;       // x-group
  const int x0  = xg * 4;

  // BN fold: r = acc*scale + shift
  float qs[4], qsh[4], ks[4], ksh[4], vs[4], vsh[4];
  #pragma unroll
  for (int cc = 0; cc < 4; ++cc) {
    const int c = co0 + cc;
    float iv;
    iv = q_g[c] * rsqrtf(q_va[c] + 1e-5f);
    qs[cc] = iv; qsh[cc] = q_b[c] * iv + q_be[c] - q_m[c] * iv;
    iv = k_g[c] * rsqrtf(k_va[c] + 1e-5f);
    ks[cc] = iv; ksh[cc] = k_b[c] * iv + k_be[c] - k_m[c] * iv;
    iv = v_g[c] * rsqrtf(v_va[c] + 1e-5f);
    vs[cc] = iv; vsh[cc] = v_b[c] * iv + v_be[c] - v_m[c] * iv;
  }

  const float* srcA = f1 + (size_t)b * 256 * 4096;
  const float* srcB = f2 + (size_t)b * 256 * 4096;

  // staging regs: [ci-sub][pass]; pass 0 = slot t, pass 1 = slot 256+t (t<32)
  float4 rA[2][2], rB[2][2];
  const int row0 = t >> 4;            // pass-0 row (0..15)
  const int row1 = 16 + (t >> 4);     // pass-1 row (16..17), only t<32
  const int grp  = t & 15;

  #define LOADREGS(R)                                                         \
    {                                                                         \
      _Pragma("unroll")                                                       \
      for (int s = 0; s < 2; ++s) {                                           \
        const int ci = (R) * 2 + s;                                           \
        const size_t cb = (size_t)ci * 4096;                                  \
        {                                                                     \
          const int gy = y0 - 1 + row0;                                       \
          float4 a = make_float4(0.f, 0.f, 0.f, 0.f);                         \
          float4 bb = make_float4(0.f, 0.f, 0.f, 0.f);                        \
          if (gy >= 0 && gy <= 63) {                                          \
            a  = *(const float4*)(srcA + cb + gy * 64 + grp * 4);             \
            bb = *(const float4*)(srcB + cb + gy * 64 + grp * 4);             \
          }                                                                   \
          rA[s][0] = a; rB[s][0] = bb;                                        \
        }                                                                     \
        if (t < 32) {                                                         \
          const int gy = y0 - 1 + row1;                                       \
          float4 a = make_float4(0.f, 0.f, 0.f, 0.f);                         \
          float4 bb = make_float4(0.f, 0.f, 0.f, 0.f);                        \
          if (gy >= 0 && gy <= 63) {                                          \
            a  = *(const float4*)(srcA + cb + gy * 64 + grp * 4);             \
            bb = *(const float4*)(srcB + cb + gy * 64 + grp * 4);             \
          }                                                                   \
          rA[s][1] = a; rB[s][1] = bb;                                        \
        }                                                                     \
      }                                                                       \
    }

  float accQ[4][4] = {{0.f}}, accK[4][4] = {{0.f}}, accV[4][4] = {{0.f}};

  LOADREGS(0);

  for (int r = 0; r < 128; ++r) {
    __syncthreads();  // previous round's LDS reads complete
    #pragma unroll
    for (int s = 0; s < 2; ++s) {
      *(float4*)(&tA[s][TPAD + row0 * TSTR + grp * 4]) = rA[s][0];
      *(float4*)(&tB[s][TPAD + row0 * TSTR + grp * 4]) = rB[s][0];
      if (t < 32) {
        *(float4*)(&tA[s][TPAD + row1 * TSTR + grp * 4]) = rA[s][1];
        *(float4*)(&tB[s][TPAD + row1 * TSTR + grp * 4]) = rB[s][1];
      }
    }
    if (r < 127) LOADREGS(r + 1);   // issue-early: in flight during compute
    __syncthreads();  // tiles ready

    #pragma unroll
    for (int s = 0; s < 2; ++s) {
      const int ci = 2 * r + s;
      // load halo'd columns x0-1..x0+4 for 3 input rows, both tensors
      float cA[3][6], cB[3][6];
      #pragma unroll
      for (int ky = 0; ky < 3; ++ky) {
        const float* pA = &tA[s][TPAD + (ry + ky) * TSTR + x0];
        const float* pB = &tB[s][TPAD + (ry + ky) * TSTR + x0];
        const float2 a2 = *(const float2*)(pA - 2);
        const float4 a4 = *(const float4*)(pA);
        const float2 a6 = *(const float2*)(pA + 4);
        cA[ky][0] = a2.y; cA[ky][1] = a4.x; cA[ky][2] = a4.y;
        cA[ky][3] = a4.z; cA[ky][4] = a4.w; cA[ky][5] = a6.x;
        const float2 b2 = *(const float2*)(pB - 2);
        const float4 b4 = *(const float4*)(pB);
        const float2 b6 = *(const float2*)(pB + 4);
        cB[ky][0] = b2.y; cB[ky][1] = b4.x; cB[ky][2] = b4.y;
        cB[ky][3] = b4.z; cB[ky][4] = b4.w; cB[ky][5] = b6.x;
      }
      if (xg == 0) {
        #pragma unroll
        for (int ky = 0; ky < 3; ++ky) { cA[ky][0] = 0.f; cB[ky][0] = 0.f; }
      }
      if (xg == 15) {
        #pragma unroll
        for (int ky = 0; ky < 3; ++ky) { cA[ky][5] = 0.f; cB[ky][5] = 0.f; }
      }

      #pragma unroll
      for (int ky = 0; ky < 3; ++ky) {
        #pragma unroll
        for (int cc = 0; cc < 4; ++cc) {
          const size_t wb = ((size_t)(co0 + cc) * 256 + ci) * 9 + ky * 3;
          const float q0 = q_w[wb], q1 = q_w[wb + 1], q2 = q_w[wb + 2];
          const float k0 = k_w[wb], k1 = k_w[wb + 1], k2 = k_w[wb + 2];
          const float v0 = v_w[wb], v1 = v_w[wb + 1], v2 = v_w[wb + 2];
          #pragma unroll
          for (int px = 0; px < 4; ++px) {
            accQ[cc][px] += cB[ky][px] * q0 + cB[ky][px + 1] * q1 + cB[ky][px + 2] * q2;
            accK[cc][px] += cA[ky][px] * k0 + cA[ky][px + 1] * k1 + cA[ky][px + 2] * k2;
            accV[cc][px] += cA[ky][px] * v0 + cA[ky][px + 1] * v1 + cA[ky][px + 2] * v2;
          }
        }
      }
    }
  }

  // epilogue: BN + ReLU, float4 stores
  const size_t ob = ((size_t)b * 64 + co0) * 4096 + (size_t)(y0 + ry) * 64 + x0;
  #pragma unroll
  for (int cc = 0; cc < 4; ++cc) {
    float4 o;
    o.x = fmaxf(accQ[cc][0] * qs[cc] + qsh[cc], 0.f);
    o.y = fmaxf(accQ[cc][1] * qs[cc] + qsh[cc], 0.f);
    o.z = fmaxf(accQ[cc][2] * qs[cc] + qsh[cc], 0.f);
    o.w = fmaxf(accQ[cc][3] * qs[cc] + qsh[cc], 0.f);
    *(float4*)(qo + ob + (size_t)cc * 4096) = o;
    o.x = fmaxf(accK[cc][0] * ks[cc] + ksh[cc], 0.f);
    o.y = fmaxf(accK[cc][1] * ks[cc] + ksh[cc], 0.f);
    o.z = fmaxf(accK[cc][2] * ks[cc] + ksh[cc], 0.f);
    o.w = fmaxf(accK[cc][3] * ks[cc] + ksh[cc], 0.f);
    *(float4*)(ko + ob + (size_t)cc * 4096) = o;
    o.x = fmaxf(accV[cc][0] * vs[cc] + vsh[cc], 0.f);
    o.y = fmaxf(accV[cc][1] * vs[cc] + vsh[cc], 0.f);
    o.z = fmaxf(accV[cc][2] * vs[cc] + vsh[cc], 0.f);
    o.w = fmaxf(accV[cc][3] * vs[cc] + vsh[cc], 0.f);
    *(float4*)(vo + ob + (size_t)cc * 4096) = o;
  }
}

// ---------------------------------------------------------------------------
// Flash-style attention, fp32 (unchanged from R15 — verified).
__global__ __launch_bounds__(256) void attention_flash_f32(
    const float* __restrict__ q, const float* __restrict__ k,
    const float* __restrict__ v, float* __restrict__ f)
{
  __shared__ float kp_lds[64 * 68];  // K tile [c][m] -> reused as P [n][m]
  __shared__ float vt_lds[64 * 68];  // V tile transposed [m][c]
  __shared__ float qt_lds[64 * 68];  // Q tile [c][n] -> reused for epilogue

  const int lin = blockIdx.x;
  const int b = (lin & 7) >> 1;
  const int nb = ((lin >> 3) << 1) | (lin & 1);
  const int n0 = nb * 64;

  const int t = threadIdx.x;
  const int mg = t & 15;
  const int ng = t >> 4;

  const float* qb = q + (size_t)b * 64 * 4096;
  const float* kb = k + (size_t)b * 64 * 4096;
  const float* vb = v + (size_t)b * 64 * 4096;

  {
    const int nn = t & 15;
    const int c0 = t >> 4;
    #pragma unroll
    for (int p = 0; p < 4; ++p) {
      const int c = c0 + p * 16;
      const float4 val = *(const float4*)(qb + (size_t)c * 4096 + n0 + nn * 4);
      *(float4*)(qt_lds + c * 68 + nn * 4) = val;
    }
  }

  float acc[4][4] = {{0.f}};
  float m_run[4], l_run[4];
  #pragma unroll
  for (int i = 0; i < 4; ++i) { m_run[i] = -1e30f; l_run[i] = 0.f; }

  const int kc  = t >> 2;
  const int kf  = t & 3;
  const int vm4 = t & 15;
  const int vc0 = t >> 4;

  float4 kreg[4], vreg[4];
  #pragma unroll
  for (int r = 0; r < 4; ++r)
    kreg[r] = *(const float4*)(kb + (size_t)kc * 4096 + (kf + 4 * r) * 4);
  #pragma unroll
  for (int p = 0; p < 4; ++p)
    vreg[p] = *(const float4*)(vb + (size_t)(vc0 + 16 * p) * 4096 + vm4 * 4);

  for (int tile = 0; tile < 64; ++tile) {
    __syncthreads();

    #pragma unroll
    for (int r = 0; r < 4; ++r)
      *(float4*)(kp_lds + kc * 68 + (kf + 4 * r) * 4) = kreg[r];
    #pragma unroll
    for (int p = 0; p < 4; ++p) {
      const float4 vv = vreg[p];
      const int c = vc0 + 16 * p;
      vt_lds[(vm4 * 4 + 0) * 68 + c] = vv.x;
      vt_lds[(vm4 * 4 + 1) * 68 + c] = vv.y;
      vt_lds[(vm4 * 4 + 2) * 68 + c] = vv.z;
      vt_lds[(vm4 * 4 + 3) * 68 + c] = vv.w;
    }
    if (tile < 63) {
      const int m0 = (tile + 1) * 64;
      #pragma unroll
      for (int r = 0; r < 4; ++r)
        kreg[r] = *(const float4*)(kb + (size_t)kc * 4096 + m0 + (kf + 4 * r) * 4);
      #pragma unroll
      for (int p = 0; p < 4; ++p)
        vreg[p] = *(const float4*)(vb + (size_t)(vc0 + 16 * p) * 4096 + m0 + vm4 * 4);
    }
    __syncthreads();

    float s[4][4] = {{0.f}};
    #pragma unroll 8
    for (int c = 0; c < 64; ++c) {
      const float4 q4 = *(const float4*)(qt_lds + c * 68 + 4 * ng);
      const float4 k4 = *(const float4*)(kp_lds + c * 68 + 4 * mg);
      const float qa[4] = {q4.x, q4.y, q4.z, q4.w};
      const float ka[4] = {k4.x, k4.y, k4.z, k4.w};
      #pragma unroll
      for (int i = 0; i < 4; ++i)
        #pragma unroll
        for (int j = 0; j < 4; ++j)
          s[i][j] += qa[i] * ka[j];
    }

    #pragma unroll
    for (int i = 0; i < 4; ++i) {
      float rm = fmaxf(fmaxf(s[i][0], s[i][1]), fmaxf(s[i][2], s[i][3]));
      rm = fmaxf(rm, __shfl_xor(rm, 1));
      rm = fmaxf(rm, __shfl_xor(rm, 2));
      rm = fmaxf(rm, __shfl_xor(rm, 4));
      rm = fmaxf(rm, __shfl_xor(rm, 8));
      const float mn = fmaxf(m_run[i], rm);
      const float al = __expf(m_run[i] - mn);
      m_run[i] = mn;
      float rs = 0.f;
      #pragma unroll
      for (int j = 0; j < 4; ++j) { s[i][j] = __expf(s[i][j] - mn); rs += s[i][j]; }
      rs += __shfl_xor(rs, 1);
      rs += __shfl_xor(rs, 2);
      rs += __shfl_xor(rs, 4);
      rs += __shfl_xor(rs, 8);
      l_run[i] = al * l_run[i] + rs;
      #pragma unroll
      for (int j = 0; j < 4; ++j) acc[i][j] *= al;
    }

    __syncthreads();
    #pragma unroll
    for (int i = 0; i < 4; ++i)
      *(float4*)(kp_lds + (4 * ng + i) * 68 + 4 * mg) =
          make_float4(s[i][0], s[i][1], s[i][2], s[i][3]);
    __syncthreads();

    #pragma unroll 4
    for (int m4 = 0; m4 < 16; ++m4) {
      float pa[4][4], va[4][4];
      #pragma unroll
      for (int i = 0; i < 4; ++i) {
        const float4 p4 = *(const float4*)(kp_lds + (4 * ng + i) * 68 + m4 * 4);
        pa[i][0] = p4.x; pa[i][1] = p4.y; pa[i][2] = p4.z; pa[i][3] = p4.w;
      }
      #pragma unroll
      for (int jm = 0; jm < 4; ++jm) {
        const float4 v4 = *(const float4*)(vt_lds + (m4 * 4 + jm) * 68 + 4 * mg);
        va[jm][0] = v4.x; va[jm][1] = v4.y; va[jm][2] = v4.z; va[jm][3] = v4.w;
      }
      #pragma unroll
      for (int i = 0; i < 4; ++i)
        #pragma unroll
        for (int jm = 0; jm < 4; ++jm)
          #pragma unroll
          for (int j = 0; j < 4; ++j)
            acc[i][j] += pa[i][jm] * va[jm][j];
    }
  }

  __syncthreads();
  #pragma unroll
  for (int i = 0; i < 4; ++i) {
    const float inv = 1.f / l_run[i];
    #pragma unroll
    for (int j = 0; j < 4; ++j)
      qt_lds[(4 * mg + j) * 68 + 4 * ng + i] = acc[i][j] * inv;
  }
  __syncthreads();
  {
    const int c = t >> 2;
    #pragma unroll
    for (int r = 0; r < 4; ++r) {
      const int f4i = (t & 3) + 4 * r;
      *(float4*)(f + ((size_t)b * 64 + c) * 4096 + n0 + f4i * 4) =
          *(const float4*)(qt_lds + c * 68 + f4i * 4);
    }
  }
}

// ---------------------------------------------------------------------------
// conv_r: conv3x3 + BN + ReLU + residual.  Cin=64 -> Cout=256.  fp32.
// Same register-blocked structure. fin [4][64][4096]; res/out [4][256][4096].
// grid (4, 64, 4): x = 16-row group, y = co-group (4), z = b.  block 256.
__global__ __launch_bounds__(256, 1) void conv_r_f32(
    const float* __restrict__ fin, const float* __restrict__ w,
    const float* __restrict__ bi, const float* __restrict__ g,
    const float* __restrict__ be, const float* __restrict__ mu,
    const float* __restrict__ va, const float* __restrict__ res,
    float* __restrict__ out)
{
  __shared__ float tA[2][TSZ];

  const int b   = blockIdx.z;
  const int co0 = blockIdx.y * 4;
  const int y0  = blockIdx.x * 16;
  const int t   = threadIdx.x;
  const int ry  = t >> 4;
  const int xg  = t & 15;
  const int x0  = xg * 4;

  float sc[4], sh[4];
  #pragma unroll
  for (int cc = 0; cc < 4; ++cc) {
    const int c = co0 + cc;
    const float iv = g[c] * rsqrtf(va[c] + 1e-5f);
    sc[cc] = iv; sh[cc] = bi[c] * iv + be[c] - mu[c] * iv;
  }

  const float* srcA = fin + (size_t)b * 64 * 4096;
  float4 rA[2][2];
  const int row0 = t >> 4;
  const int row1 = 16 + (t >> 4);
  const int grp  = t & 15;

  #define LOADR(R)                                                            \
    {                                                                         \
      _Pragma("unroll")                                                       \
      for (int s = 0; s < 2; ++s) {                                           \
        const int ci = (R) * 2 + s;                                           \
        const size_t cb = (size_t)ci * 4096;                                  \
        {                                                                     \
          const int gy = y0 - 1 + row0;                                       \
          float4 a = make_float4(0.f, 0.f, 0.f, 0.f);                         \
          if (gy >= 0 && gy <= 63)                                            \
            a = *(const float4*)(srcA + cb + gy * 64 + grp * 4);              \
          rA[s][0] = a;                                                       \
        }                                                                     \
        if (t < 32) {                                                         \
          const int gy = y0 - 1 + row1;                                       \
          float4 a = make_float4(0.f, 0.f, 0.f, 0.f);                         \
          if (gy >= 0 && gy <= 63)                                            \
            a = *(const float4*)(srcA + cb + gy * 64 + grp * 4);              \
          rA[s][1] = a;                                                       \
        }                                                                     \
      }                                                                       \
    }

  float acc[4][4] = {{0.f}};
  LOADR(0);

  for (int r = 0; r < 32; ++r) {
    __syncthreads();
    #pragma unroll
    for (int s = 0; s < 2; ++s) {
      *(float4*)(&tA[s][TPAD + row0 * TSTR + grp * 4]) = rA[s][0];
      if (t < 32)
        *(float4*)(&tA[s][TPAD + row1 * TSTR + grp * 4]) = rA[s][1];
    }
    if (r < 31) LOADR(r + 1);
    __syncthreads();

    #pragma unroll
    for (int s = 0; s < 2; ++s) {
      const int ci = 2 * r + s;
      float cA[3][6];
      #pragma unroll
      for (int ky = 0; ky < 3; ++ky) {
        const float* pA = &tA[s][TPAD + (ry + ky) * TSTR + x0];
        const float2 a2 = *(const float2*)(pA - 2);
        const float4 a4 = *(const float4*)(pA);
        const float2 a6 = *(const float2*)(pA + 4);
        cA[ky][0] = a2.y; cA[ky][1] = a4.x; cA[ky][2] = a4.y;
        cA[ky][3] = a4.z; cA[ky][4] = a4.w; cA[ky][5] = a6.x;
      }
      if (xg == 0) {
        #pragma unroll
        for (int ky = 0; ky < 3; ++ky) cA[ky][0] = 0.f;
      }
      if (xg == 15) {
        #pragma unroll
        for (int ky = 0; ky < 3; ++ky) cA[ky][5] = 0.f;
      }

      #pragma unroll
      for (int ky = 0; ky < 3; ++ky) {
        #pragma unroll
        for (int cc = 0; cc < 4; ++cc) {
          const size_t wb = ((size_t)(co0 + cc) * 64 + ci) * 9 + ky * 3;
          const float w0 = w[wb], w1 = w[wb + 1], w2 = w[wb + 2];
          #pragma unroll
          for (int px = 0; px < 4; ++px)
            acc[cc][px] += cA[ky][px] * w0 + cA[ky][px + 1] * w1 + cA[ky][px + 2] * w2;
        }
      }
    }
  }

  const size_t ob = ((size_t)b * 256 + co0) * 4096 + (size_t)(y0 + ry) * 64 + x0;
  #pragma unroll
  for (int cc = 0; cc < 4; ++cc) {
    const float4 rv = *(const float4*)(res + ob + (size_t)cc * 4096);
    float4 o;
    o.x = rv.x + fmaxf(acc[cc][0] * sc[cc] + sh[cc], 0.f);
    o.y = rv.y + fmaxf(acc[cc][1] * sc[cc] + sh[cc], 0.f);
    o.z = rv.z + fmaxf(acc[cc][2] * sc[cc] + sh[cc], 0.f);
    o.w = rv.w + fmaxf(acc[cc][3] * sc[cc] + sh[cc], 0.f);
    *(float4*)(out + ob + (size_t)cc * 4096) = o;
  }
}

// ---------------------------------------------------------------------------
extern "C" void kernel_launch(void* const* d_in, const int* in_sizes, int n_in,
                              void* d_out, int out_size, void* d_ws, size_t ws_size,
                              hipStream_t stream) {
  const float* f1 = (const float*)d_in[0];
  const float* f2 = (const float*)d_in[1];
  const float* qw = (const float*)d_in[2];  const float* qb = (const float*)d_in[3];
  const float* qg = (const float*)d_in[4];  const float* qbe = (const float*)d_in[5];
  const float* qm = (const float*)d_in[6];  const float* qv = (const float*)d_in[7];
  const float* kw = (const float*)d_in[8];  const float* kb = (const float*)d_in[9];
  const float* kg = (const float*)d_in[10]; const float* kbe = (const float*)d_in[11];
  const float* km = (const float*)d_in[12]; const float* kv = (const float*)d_in[13];
  const float* vw = (const float*)d_in[14]; const float* vb = (const float*)d_in[15];
  const float* vg = (const float*)d_in[16]; const float* vbe = (const float*)d_in[17];
  const float* vm = (const float*)d_in[18]; const float* vv = (const float*)d_in[19];
  const float* rw = (const float*)d_in[20]; const float* rb = (const float*)d_in[21];
  const float* rg = (const float*)d_in[22]; const float* rbe = (const float*)d_in[23];
  const float* rm = (const float*)d_in[24]; const float* rv = (const float*)d_in[25];

  hipStreamCaptureStatus cap = hipStreamCaptureStatusNone;
  unsigned long long capid = 0;
  const hipError_t ce = hipStreamGetCaptureInfo(stream, &cap, &capid);
  const bool capturing = (ce == hipSuccess) && (cap != hipStreamCaptureStatusNone);

  // Workspace: q,k,v,f fp32 [4][64][4096] = 4 MB each (ws_size = 256 MB).
  const size_t SZ1 = (size_t)4 * 64 * 4096 * 4;
  float* qp = (float*)d_ws;
  float* kp = (float*)((char*)d_ws + SZ1);
  float* vp = (float*)((char*)d_ws + 2 * SZ1);
  float* fp = (float*)((char*)d_ws + 3 * SZ1);

  convqkv_f32<<<dim3(4, 16, 4), 256, 0, stream>>>(
      f1, f2,
      qw, qb, qg, qbe, qm, qv,
      kw, kb, kg, kbe, km, kv,
      vw, vb, vg, vbe, vm, vv,
      qp, kp, vp);
  attention_flash_f32<<<dim3(256), 256, 0, stream>>>(qp, kp, vp, fp);
  conv_r_f32<<<dim3(4, 64, 4), 256, 0, stream>>>(fp, rw, rb, rg, rbe, rm, rv,
                                                 f1, (float*)d_out);

  if (!capturing) {
    const hipError_t le = hipGetLastError();
    const hipError_t se = hipStreamSynchronize(stream);
    float h[4] = {0, 0, 0, 0};
    (void)hipMemcpy(h, d_out, 16, hipMemcpyDeviceToHost);
    fprintf(stderr,
        "ATHENA_R17 fused-conv-retry le=%d sync=%d out=[%g %g %g %g]\n",
        (int)le, (int)se, h[0], h[1], h[2], h[3]);
    fflush(stderr);
  }
}

// Round 4
// 1193.231 us; speedup vs baseline: 4.3537x; 1.2120x over previous
//
#include <hip/hip_runtime.h>
#include <cstdio>

// ============================================================================
// ROUND 18: conv occupancy + weight-path fix.
// R17 counters: convqkv 950us, Occupancy 12% (=1 wave/SIMD, grid 256 = 1
// block/CU), VALUBusy 23%, SGPR 112 (per-round weight s_loads missing scalar
// cache -> ~200cy L2 latency x ~14 batches/round, fully exposed at 1 wave).
// Also: prefetch was issued BEFORE a barrier -> implicit vmcnt(0) drained it.
// Fixes: (1) co-split 4->2, grid 512 = 2 blocks/CU; (2) weights staged
// through LDS (broadcast reads), double-buffered in regs; (3) prefetch moved
// after the compute-side barrier; (4) LDS stride 64->68. Same for conv_r.
// Attention: prefetch reorder only.
// ============================================================================

// Keeps the harness-stub identifier name (unused utility).
__global__ __launch_bounds__(256) void CrossModalityPositionAttention_56556129354448_kernel(
    float* dst, float val, int n)
{
  const int i = blockIdx.x * 256 + threadIdx.x;
  if (i < n) dst[i] = val;
}

// ---------------------------------------------------------------------------
#define TROWS 18
#define TSTR  68
#define TPAD  8
#define TSZ   (TPAD + TROWS * TSTR + TPAD)   // 1240 floats

// Fused q/k/v conv3x3 + BN + ReLU.  q = conv(f2), k = conv(f1), v = conv(f1).
// Cin=256 -> Cout=64 each.  In: NCHW [4][256][64][64] fp32.
// Out: three [4][64][4096] fp32.
// grid (4, 32, 4): x = 16-row group, y = co-group (2 couts), z = b. block 256.
// Thread (ry = t>>4, xg = t&15): 4 px, 2 couts, q+k+v -> 24 accs.
// Weights: 108 floats/round (3 tensors x 2 co x 2 ci x 9) staged via LDS.
__global__ __launch_bounds__(256, 2) void convqkv_f32(
    const float* __restrict__ f1, const float* __restrict__ f2,
    const float* __restrict__ q_w, const float* __restrict__ q_b,
    const float* __restrict__ q_g, const float* __restrict__ q_be,
    const float* __restrict__ q_m, const float* __restrict__ q_va,
    const float* __restrict__ k_w, const float* __restrict__ k_b,
    const float* __restrict__ k_g, const float* __restrict__ k_be,
    const float* __restrict__ k_m, const float* __restrict__ k_va,
    const float* __restrict__ v_w, const float* __restrict__ v_b,
    const float* __restrict__ v_g, const float* __restrict__ v_be,
    const float* __restrict__ v_m, const float* __restrict__ v_va,
    float* __restrict__ qo, float* __restrict__ ko, float* __restrict__ vo)
{
  __shared__ float tA[2][TSZ];   // f1 tiles (ci 2r, 2r+1)
  __shared__ float tB[2][TSZ];   // f2 tiles
  __shared__ float wlds[112];    // 108 weights: [T][cc][s*9 + ky*3 + kx]

  const int b   = blockIdx.z;
  const int co0 = blockIdx.y * 2;
  const int y0  = blockIdx.x * 16;
  const int t   = threadIdx.x;
  const int ry  = t >> 4;        // output row within tile (0..15)
  const int xg  = t & 15;
  const int x0  = xg * 4;

  // BN fold: r = acc*scale + shift
  float qs[2], qsh[2], ks[2], ksh[2], vs[2], vsh[2];
  #pragma unroll
  for (int cc = 0; cc < 2; ++cc) {
    const int c = co0 + cc;
    float iv;
    iv = q_g[c] * rsqrtf(q_va[c] + 1e-5f);
    qs[cc] = iv; qsh[cc] = q_b[c] * iv + q_be[c] - q_m[c] * iv;
    iv = k_g[c] * rsqrtf(k_va[c] + 1e-5f);
    ks[cc] = iv; ksh[cc] = k_b[c] * iv + k_be[c] - k_m[c] * iv;
    iv = v_g[c] * rsqrtf(v_va[c] + 1e-5f);
    vs[cc] = iv; vsh[cc] = v_b[c] * iv + v_be[c] - v_m[c] * iv;
  }

  const float* srcA = f1 + (size_t)b * 256 * 4096;
  const float* srcB = f2 + (size_t)b * 256 * 4096;

  // input staging regs
  float4 rA[2][2], rB[2][2];
  const int row0 = t >> 4;          // pass-0 row (0..15)
  const int row1 = 16 + (t >> 4);   // pass-1 row (16..17), only t<32
  const int grp  = t & 15;

  // weight staging: t<108 -> seg = t/18 in 0..5: T = seg>>1, cc = seg&1;
  // kk = t%18 = s*9 + ky*3 + kx.  addr for round R = wbase0 + 18R.
  const int wseg = t / 18;
  const int wkk  = t - wseg * 18;
  const float* wptr = (wseg < 2) ? q_w : ((wseg < 4) ? k_w : v_w);
  const int wbase0 = (co0 + (wseg & 1)) * 256 * 9 + wkk;
  float wreg = 0.f;

  #define LOADREGS(R)                                                         \
    {                                                                         \
      _Pragma("unroll")                                                       \
      for (int s = 0; s < 2; ++s) {                                           \
        const size_t cb = (size_t)((R) * 2 + s) * 4096;                       \
        {                                                                     \
          const int gy = y0 - 1 + row0;                                       \
          float4 a = make_float4(0.f, 0.f, 0.f, 0.f);                         \
          float4 bb = make_float4(0.f, 0.f, 0.f, 0.f);                        \
          if (gy >= 0 && gy <= 63) {                                          \
            a  = *(const float4*)(srcA + cb + gy * 64 + grp * 4);             \
            bb = *(const float4*)(srcB + cb + gy * 64 + grp * 4);             \
          }                                                                   \
          rA[s][0] = a; rB[s][0] = bb;                                        \
        }                                                                     \
        if (t < 32) {                                                         \
          const int gy = y0 - 1 + row1;                                       \
          float4 a = make_float4(0.f, 0.f, 0.f, 0.f);                         \
          float4 bb = make_float4(0.f, 0.f, 0.f, 0.f);                        \
          if (gy >= 0 && gy <= 63) {                                          \
            a  = *(const float4*)(srcA + cb + gy * 64 + grp * 4);             \
            bb = *(const float4*)(srcB + cb + gy * 64 + grp * 4);             \
          }                                                                   \
          rA[s][1] = a; rB[s][1] = bb;                                        \
        }                                                                     \
      }                                                                       \
      if (t < 108) wreg = wptr[wbase0 + (R) * 18];                            \
    }

  float accQ[2][4] = {{0.f}}, accK[2][4] = {{0.f}}, accV[2][4] = {{0.f}};

  LOADREGS(0);

  for (int r = 0; r < 128; ++r) {
    __syncthreads();  // prior round's LDS reads complete (vmcnt==0 here)
    #pragma unroll
    for (int s = 0; s < 2; ++s) {
      *(float4*)(&tA[s][TPAD + row0 * TSTR + grp * 4]) = rA[s][0];
      *(float4*)(&tB[s][TPAD + row0 * TSTR + grp * 4]) = rB[s][0];
      if (t < 32) {
        *(float4*)(&tA[s][TPAD + row1 * TSTR + grp * 4]) = rA[s][1];
        *(float4*)(&tB[s][TPAD + row1 * TSTR + grp * 4]) = rB[s][1];
      }
    }
    if (t < 108) wlds[t] = wreg;
    __syncthreads();  // tiles + weights ready
    // prefetch AFTER the barrier: loads stay in flight under the FMA phase
    if (r < 127) LOADREGS(r + 1);

    #pragma unroll
    for (int s = 0; s < 2; ++s) {
      float cA[3][6], cB[3][6];
      #pragma unroll
      for (int ky = 0; ky < 3; ++ky) {
        const float* pA = &tA[s][TPAD + (ry + ky) * TSTR + x0];
        const float* pB = &tB[s][TPAD + (ry + ky) * TSTR + x0];
        const float2 a2 = *(const float2*)(pA - 2);
        const float4 a4 = *(const float4*)(pA);
        const float2 a6 = *(const float2*)(pA + 4);
        cA[ky][0] = a2.y; cA[ky][1] = a4.x; cA[ky][2] = a4.y;
        cA[ky][3] = a4.z; cA[ky][4] = a4.w; cA[ky][5] = a6.x;
        const float2 b2 = *(const float2*)(pB - 2);
        const float4 b4 = *(const float4*)(pB);
        const float2 b6 = *(const float2*)(pB + 4);
        cB[ky][0] = b2.y; cB[ky][1] = b4.x; cB[ky][2] = b4.y;
        cB[ky][3] = b4.z; cB[ky][4] = b4.w; cB[ky][5] = b6.x;
      }
      if (xg == 0) {
        #pragma unroll
        for (int ky = 0; ky < 3; ++ky) { cA[ky][0] = 0.f; cB[ky][0] = 0.f; }
      }
      if (xg == 15) {
        #pragma unroll
        for (int ky = 0; ky < 3; ++ky) { cA[ky][5] = 0.f; cB[ky][5] = 0.f; }
      }

      #pragma unroll
      for (int ky = 0; ky < 3; ++ky) {
        #pragma unroll
        for (int cc = 0; cc < 2; ++cc) {
          const int wb = cc * 18 + s * 9 + ky * 3;
          const float q0 = wlds[wb],      q1 = wlds[wb + 1],      q2 = wlds[wb + 2];
          const float k0 = wlds[36 + wb], k1 = wlds[36 + wb + 1], k2 = wlds[36 + wb + 2];
          const float v0 = wlds[72 + wb], v1 = wlds[72 + wb + 1], v2 = wlds[72 + wb + 2];
          #pragma unroll
          for (int px = 0; px < 4; ++px) {
            accQ[cc][px] += cB[ky][px] * q0 + cB[ky][px + 1] * q1 + cB[ky][px + 2] * q2;
            accK[cc][px] += cA[ky][px] * k0 + cA[ky][px + 1] * k1 + cA[ky][px + 2] * k2;
            accV[cc][px] += cA[ky][px] * v0 + cA[ky][px + 1] * v1 + cA[ky][px + 2] * v2;
          }
        }
      }
    }
  }

  // epilogue: BN + ReLU, float4 stores
  const size_t ob = ((size_t)b * 64 + co0) * 4096 + (size_t)(y0 + ry) * 64 + x0;
  #pragma unroll
  for (int cc = 0; cc < 2; ++cc) {
    float4 o;
    o.x = fmaxf(accQ[cc][0] * qs[cc] + qsh[cc], 0.f);
    o.y = fmaxf(accQ[cc][1] * qs[cc] + qsh[cc], 0.f);
    o.z = fmaxf(accQ[cc][2] * qs[cc] + qsh[cc], 0.f);
    o.w = fmaxf(accQ[cc][3] * qs[cc] + qsh[cc], 0.f);
    *(float4*)(qo + ob + (size_t)cc * 4096) = o;
    o.x = fmaxf(accK[cc][0] * ks[cc] + ksh[cc], 0.f);
    o.y = fmaxf(accK[cc][1] * ks[cc] + ksh[cc], 0.f);
    o.z = fmaxf(accK[cc][2] * ks[cc] + ksh[cc], 0.f);
    o.w = fmaxf(accK[cc][3] * ks[cc] + ksh[cc], 0.f);
    *(float4*)(ko + ob + (size_t)cc * 4096) = o;
    o.x = fmaxf(accV[cc][0] * vs[cc] + vsh[cc], 0.f);
    o.y = fmaxf(accV[cc][1] * vs[cc] + vsh[cc], 0.f);
    o.z = fmaxf(accV[cc][2] * vs[cc] + vsh[cc], 0.f);
    o.w = fmaxf(accV[cc][3] * vs[cc] + vsh[cc], 0.f);
    *(float4*)(vo + ob + (size_t)cc * 4096) = o;
  }
}

// ---------------------------------------------------------------------------
// Flash-style attention, fp32 (R15 structure; prefetch moved after barrier).
__global__ __launch_bounds__(256) void attention_flash_f32(
    const float* __restrict__ q, const float* __restrict__ k,
    const float* __restrict__ v, float* __restrict__ f)
{
  __shared__ float kp_lds[64 * 68];
  __shared__ float vt_lds[64 * 68];
  __shared__ float qt_lds[64 * 68];

  const int lin = blockIdx.x;
  const int b = (lin & 7) >> 1;
  const int nb = ((lin >> 3) << 1) | (lin & 1);
  const int n0 = nb * 64;

  const int t = threadIdx.x;
  const int mg = t & 15;
  const int ng = t >> 4;

  const float* qb = q + (size_t)b * 64 * 4096;
  const float* kb = k + (size_t)b * 64 * 4096;
  const float* vb = v + (size_t)b * 64 * 4096;

  {
    const int nn = t & 15;
    const int c0 = t >> 4;
    #pragma unroll
    for (int p = 0; p < 4; ++p) {
      const int c = c0 + p * 16;
      const float4 val = *(const float4*)(qb + (size_t)c * 4096 + n0 + nn * 4);
      *(float4*)(qt_lds + c * 68 + nn * 4) = val;
    }
  }

  float acc[4][4] = {{0.f}};
  float m_run[4], l_run[4];
  #pragma unroll
  for (int i = 0; i < 4; ++i) { m_run[i] = -1e30f; l_run[i] = 0.f; }

  const int kc  = t >> 2;
  const int kf  = t & 3;
  const int vm4 = t & 15;
  const int vc0 = t >> 4;

  float4 kreg[4], vreg[4];
  #pragma unroll
  for (int r = 0; r < 4; ++r)
    kreg[r] = *(const float4*)(kb + (size_t)kc * 4096 + (kf + 4 * r) * 4);
  #pragma unroll
  for (int p = 0; p < 4; ++p)
    vreg[p] = *(const float4*)(vb + (size_t)(vc0 + 16 * p) * 4096 + vm4 * 4);

  for (int tile = 0; tile < 64; ++tile) {
    __syncthreads();

    #pragma unroll
    for (int r = 0; r < 4; ++r)
      *(float4*)(kp_lds + kc * 68 + (kf + 4 * r) * 4) = kreg[r];
    #pragma unroll
    for (int p = 0; p < 4; ++p) {
      const float4 vv = vreg[p];
      const int c = vc0 + 16 * p;
      vt_lds[(vm4 * 4 + 0) * 68 + c] = vv.x;
      vt_lds[(vm4 * 4 + 1) * 68 + c] = vv.y;
      vt_lds[(vm4 * 4 + 2) * 68 + c] = vv.z;
      vt_lds[(vm4 * 4 + 3) * 68 + c] = vv.w;
    }
    __syncthreads();
    // prefetch AFTER the barrier -> in flight under QK+softmax
    if (tile < 63) {
      const int m0 = (tile + 1) * 64;
      #pragma unroll
      for (int r = 0; r < 4; ++r)
        kreg[r] = *(const float4*)(kb + (size_t)kc * 4096 + m0 + (kf + 4 * r) * 4);
      #pragma unroll
      for (int p = 0; p < 4; ++p)
        vreg[p] = *(const float4*)(vb + (size_t)(vc0 + 16 * p) * 4096 + m0 + vm4 * 4);
    }

    float s[4][4] = {{0.f}};
    #pragma unroll 8
    for (int c = 0; c < 64; ++c) {
      const float4 q4 = *(const float4*)(qt_lds + c * 68 + 4 * ng);
      const float4 k4 = *(const float4*)(kp_lds + c * 68 + 4 * mg);
      const float qa[4] = {q4.x, q4.y, q4.z, q4.w};
      const float ka[4] = {k4.x, k4.y, k4.z, k4.w};
      #pragma unroll
      for (int i = 0; i < 4; ++i)
        #pragma unroll
        for (int j = 0; j < 4; ++j)
          s[i][j] += qa[i] * ka[j];
    }

    #pragma unroll
    for (int i = 0; i < 4; ++i) {
      float rm = fmaxf(fmaxf(s[i][0], s[i][1]), fmaxf(s[i][2], s[i][3]));
      rm = fmaxf(rm, __shfl_xor(rm, 1));
      rm = fmaxf(rm, __shfl_xor(rm, 2));
      rm = fmaxf(rm, __shfl_xor(rm, 4));
      rm = fmaxf(rm, __shfl_xor(rm, 8));
      const float mn = fmaxf(m_run[i], rm);
      const float al = __expf(m_run[i] - mn);
      m_run[i] = mn;
      float rs = 0.f;
      #pragma unroll
      for (int j = 0; j < 4; ++j) { s[i][j] = __expf(s[i][j] - mn); rs += s[i][j]; }
      rs += __shfl_xor(rs, 1);
      rs += __shfl_xor(rs, 2);
      rs += __shfl_xor(rs, 4);
      rs += __shfl_xor(rs, 8);
      l_run[i] = al * l_run[i] + rs;
      #pragma unroll
      for (int j = 0; j < 4; ++j) acc[i][j] *= al;
    }

    __syncthreads();
    #pragma unroll
    for (int i = 0; i < 4; ++i)
      *(float4*)(kp_lds + (4 * ng + i) * 68 + 4 * mg) =
          make_float4(s[i][0], s[i][1], s[i][2], s[i][3]);
    __syncthreads();

    #pragma unroll 4
    for (int m4 = 0; m4 < 16; ++m4) {
      float pa[4][4], va[4][4];
      #pragma unroll
      for (int i = 0; i < 4; ++i) {
        const float4 p4 = *(const float4*)(kp_lds + (4 * ng + i) * 68 + m4 * 4);
        pa[i][0] = p4.x; pa[i][1] = p4.y; pa[i][2] = p4.z; pa[i][3] = p4.w;
      }
      #pragma unroll
      for (int jm = 0; jm < 4; ++jm) {
        const float4 v4 = *(const float4*)(vt_lds + (m4 * 4 + jm) * 68 + 4 * mg);
        va[jm][0] = v4.x; va[jm][1] = v4.y; va[jm][2] = v4.z; va[jm][3] = v4.w;
      }
      #pragma unroll
      for (int i = 0; i < 4; ++i)
        #pragma unroll
        for (int jm = 0; jm < 4; ++jm)
          #pragma unroll
          for (int j = 0; j < 4; ++j)
            acc[i][j] += pa[i][jm] * va[jm][j];
    }
  }

  __syncthreads();
  #pragma unroll
  for (int i = 0; i < 4; ++i) {
    const float inv = 1.f / l_run[i];
    #pragma unroll
    for (int j = 0; j < 4; ++j)
      qt_lds[(4 * mg + j) * 68 + 4 * ng + i] = acc[i][j] * inv;
  }
  __syncthreads();
  {
    const int c = t >> 2;
    #pragma unroll
    for (int r = 0; r < 4; ++r) {
      const int f4i = (t & 3) + 4 * r;
      *(float4*)(f + ((size_t)b * 64 + c) * 4096 + n0 + f4i * 4) =
          *(const float4*)(qt_lds + c * 68 + f4i * 4);
    }
  }
}

// ---------------------------------------------------------------------------
// conv_r: conv3x3 + BN + ReLU + residual.  Cin=64 -> Cout=256.  fp32.
// grid (4, 64, 4) = 1024 blocks (4/CU).  Weights (72/round) staged via LDS.
__global__ __launch_bounds__(256, 4) void conv_r_f32(
    const float* __restrict__ fin, const float* __restrict__ w,
    const float* __restrict__ bi, const float* __restrict__ g,
    const float* __restrict__ be, const float* __restrict__ mu,
    const float* __restrict__ va, const float* __restrict__ res,
    float* __restrict__ out)
{
  __shared__ float tA[2][TSZ];
  __shared__ float wlds[80];   // 72 weights: [cc][s*9 + ky*3 + kx]

  const int b   = blockIdx.z;
  const int co0 = blockIdx.y * 4;
  const int y0  = blockIdx.x * 16;
  const int t   = threadIdx.x;
  const int ry  = t >> 4;
  const int xg  = t & 15;
  const int x0  = xg * 4;

  float sc[4], sh[4];
  #pragma unroll
  for (int cc = 0; cc < 4; ++cc) {
    const int c = co0 + cc;
    const float iv = g[c] * rsqrtf(va[c] + 1e-5f);
    sc[cc] = iv; sh[cc] = bi[c] * iv + be[c] - mu[c] * iv;
  }

  const float* srcA = fin + (size_t)b * 64 * 4096;
  float4 rA[2][2];
  const int row0 = t >> 4;
  const int row1 = 16 + (t >> 4);
  const int grp  = t & 15;

  // weight staging: t<72: seg = t/18 = cc (0..3), kk = t%18 = s*9+ky*3+kx
  const int wseg = t / 18;
  const int wkk  = t - wseg * 18;
  const int wbase0 = (co0 + wseg) * 64 * 9 + wkk;
  float wreg = 0.f;

  #define LOADR(R)                                                            \
    {                                                                         \
      _Pragma("unroll")                                                       \
      for (int s = 0; s < 2; ++s) {                                           \
        const size_t cb = (size_t)((R) * 2 + s) * 4096;                       \
        {                                                                     \
          const int gy = y0 - 1 + row0;                                       \
          float4 a = make_float4(0.f, 0.f, 0.f, 0.f);                         \
          if (gy >= 0 && gy <= 63)                                            \
            a = *(const float4*)(srcA + cb + gy * 64 + grp * 4);              \
          rA[s][0] = a;                                                       \
        }                                                                     \
        if (t < 32) {                                                         \
          const int gy = y0 - 1 + row1;                                       \
          float4 a = make_float4(0.f, 0.f, 0.f, 0.f);                         \
          if (gy >= 0 && gy <= 63)                                            \
            a = *(const float4*)(srcA + cb + gy * 64 + grp * 4);              \
          rA[s][1] = a;                                                       \
        }                                                                     \
      }                                                                       \
      if (t < 72) wreg = w[wbase0 + (R) * 18];                                \
    }

  float acc[4][4] = {{0.f}};
  LOADR(0);

  for (int r = 0; r < 32; ++r) {
    __syncthreads();
    #pragma unroll
    for (int s = 0; s < 2; ++s) {
      *(float4*)(&tA[s][TPAD + row0 * TSTR + grp * 4]) = rA[s][0];
      if (t < 32)
        *(float4*)(&tA[s][TPAD + row1 * TSTR + grp * 4]) = rA[s][1];
    }
    if (t < 72) wlds[t] = wreg;
    __syncthreads();
    if (r < 31) LOADR(r + 1);

    #pragma unroll
    for (int s = 0; s < 2; ++s) {
      float cA[3][6];
      #pragma unroll
      for (int ky = 0; ky < 3; ++ky) {
        const float* pA = &tA[s][TPAD + (ry + ky) * TSTR + x0];
        const float2 a2 = *(const float2*)(pA - 2);
        const float4 a4 = *(const float4*)(pA);
        const float2 a6 = *(const float2*)(pA + 4);
        cA[ky][0] = a2.y; cA[ky][1] = a4.x; cA[ky][2] = a4.y;
        cA[ky][3] = a4.z; cA[ky][4] = a4.w; cA[ky][5] = a6.x;
      }
      if (xg == 0) {
        #pragma unroll
        for (int ky = 0; ky < 3; ++ky) cA[ky][0] = 0.f;
      }
      if (xg == 15) {
        #pragma unroll
        for (int ky = 0; ky < 3; ++ky) cA[ky][5] = 0.f;
      }

      #pragma unroll
      for (int ky = 0; ky < 3; ++ky) {
        #pragma unroll
        for (int cc = 0; cc < 4; ++cc) {
          const int wb = cc * 18 + s * 9 + ky * 3;
          const float w0 = wlds[wb], w1 = wlds[wb + 1], w2 = wlds[wb + 2];
          #pragma unroll
          for (int px = 0; px < 4; ++px)
            acc[cc][px] += cA[ky][px] * w0 + cA[ky][px + 1] * w1 + cA[ky][px + 2] * w2;
        }
      }
    }
  }

  const size_t ob = ((size_t)b * 256 + co0) * 4096 + (size_t)(y0 + ry) * 64 + x0;
  #pragma unroll
  for (int cc = 0; cc < 4; ++cc) {
    const float4 rv = *(const float4*)(res + ob + (size_t)cc * 4096);
    float4 o;
    o.x = rv.x + fmaxf(acc[cc][0] * sc[cc] + sh[cc], 0.f);
    o.y = rv.y + fmaxf(acc[cc][1] * sc[cc] + sh[cc], 0.f);
    o.z = rv.z + fmaxf(acc[cc][2] * sc[cc] + sh[cc], 0.f);
    o.w = rv.w + fmaxf(acc[cc][3] * sc[cc] + sh[cc], 0.f);
    *(float4*)(out + ob + (size_t)cc * 4096) = o;
  }
}

// ---------------------------------------------------------------------------
extern "C" void kernel_launch(void* const* d_in, const int* in_sizes, int n_in,
                              void* d_out, int out_size, void* d_ws, size_t ws_size,
                              hipStream_t stream) {
  const float* f1 = (const float*)d_in[0];
  const float* f2 = (const float*)d_in[1];
  const float* qw = (const float*)d_in[2];  const float* qb = (const float*)d_in[3];
  const float* qg = (const float*)d_in[4];  const float* qbe = (const float*)d_in[5];
  const float* qm = (const float*)d_in[6];  const float* qv = (const float*)d_in[7];
  const float* kw = (const float*)d_in[8];  const float* kb = (const float*)d_in[9];
  const float* kg = (const float*)d_in[10]; const float* kbe = (const float*)d_in[11];
  const float* km = (const float*)d_in[12]; const float* kv = (const float*)d_in[13];
  const float* vw = (const float*)d_in[14]; const float* vb = (const float*)d_in[15];
  const float* vg = (const float*)d_in[16]; const float* vbe = (const float*)d_in[17];
  const float* vm = (const float*)d_in[18]; const float* vv = (const float*)d_in[19];
  const float* rw = (const float*)d_in[20]; const float* rb = (const float*)d_in[21];
  const float* rg = (const float*)d_in[22]; const float* rbe = (const float*)d_in[23];
  const float* rm = (const float*)d_in[24]; const float* rv = (const float*)d_in[25];

  hipStreamCaptureStatus cap = hipStreamCaptureStatusNone;
  unsigned long long capid = 0;
  const hipError_t ce = hipStreamGetCaptureInfo(stream, &cap, &capid);
  const bool capturing = (ce == hipSuccess) && (cap != hipStreamCaptureStatusNone);

  // Workspace: q,k,v,f fp32 [4][64][4096] = 4 MB each (ws_size = 256 MB).
  const size_t SZ1 = (size_t)4 * 64 * 4096 * 4;
  float* qp = (float*)d_ws;
  float* kp = (float*)((char*)d_ws + SZ1);
  float* vp = (float*)((char*)d_ws + 2 * SZ1);
  float* fp = (float*)((char*)d_ws + 3 * SZ1);

  convqkv_f32<<<dim3(4, 32, 4), 256, 0, stream>>>(
      f1, f2,
      qw, qb, qg, qbe, qm, qv,
      kw, kb, kg, kbe, km, kv,
      vw, vb, vg, vbe, vm, vv,
      qp, kp, vp);
  attention_flash_f32<<<dim3(256), 256, 0, stream>>>(qp, kp, vp, fp);
  conv_r_f32<<<dim3(4, 64, 4), 256, 0, stream>>>(fp, rw, rb, rg, rbe, rm, rv,
                                                 f1, (float*)d_out);

  if (!capturing) {
    const hipError_t le = hipGetLastError();
    const hipError_t se = hipStreamSynchronize(stream);
    float h[4] = {0, 0, 0, 0};
    (void)hipMemcpy(h, d_out, 16, hipMemcpyDeviceToHost);
    fprintf(stderr,
        "ATHENA_R18 occ+wlds le=%d sync=%d out=[%g %g %g %g]\n",
        (int)le, (int)se, h[0], h[1], h[2], h[3]);
    fflush(stderr);
  }
}

// Round 5
// 918.860 us; speedup vs baseline: 5.6537x; 1.2986x over previous
//
#include <hip/hip_runtime.h>
#include <cstdio>

// ============================================================================
// ROUND 19: kill the LDS halo reads.
// R18 counters: convqkv 575us, SQ_LDS_BANK_CONFLICT 1.13e8 (221k/block, SAME
// as R17 -> stride change irrelevant; conflicts come from the unaligned b64
// halo reads). LDS pipe/CU/round ~5750cy vs 1728 FMA cy/SIMD -> LDS-bound.
// Fix: one aligned ds_read_b128 per (tensor,ky,s); halo words via DPP
// row_shr:1 / row_shl:1 (neighbor lane's .w/.x, bound_ctrl zero-fill gives
// image x-boundary zeros free). 36 reads/round -> 12, conflict-free, no pad,
// no boundary branches. Same for conv_r. Attention unchanged.
// ============================================================================

// Keeps the harness-stub identifier name (unused utility).
__global__ __launch_bounds__(256) void CrossModalityPositionAttention_56556129354448_kernel(
    float* dst, float val, int n)
{
  const int i = blockIdx.x * 256 + threadIdx.x;
  if (i < n) dst[i] = val;
}

// ---------------------------------------------------------------------------
// DPP lane-shift helpers. Thread layout guarantees lane%16 == xg, so the
// 16-lane DPP row boundary == image x-tile boundary (tile spans full width).
__device__ __forceinline__ float dpp_left(float x) {
  // lane xg receives lane (xg-1)'s x; xg%16==0 -> 0.0f
  return __int_as_float(__builtin_amdgcn_update_dpp(
      0, __float_as_int(x), 0x111, 0xF, 0xF, true));   // row_shr:1
}
__device__ __forceinline__ float dpp_right(float x) {
  // lane xg receives lane (xg+1)'s x; xg%16==15 -> 0.0f
  return __int_as_float(__builtin_amdgcn_update_dpp(
      0, __float_as_int(x), 0x101, 0xF, 0xF, true));   // row_shl:1
}

#define CTROWS 18
#define CTSTR  64
#define CTSZ   (CTROWS * CTSTR)   // 1152 floats, no pad needed (aligned reads)

// ---------------------------------------------------------------------------
// Fused q/k/v conv3x3 + BN + ReLU.  q = conv(f2), k = conv(f1), v = conv(f1).
// Cin=256 -> Cout=64 each.  In: NCHW [4][256][64][64] fp32.
// Out: three [4][64][4096] fp32.
// grid (4, 32, 4): x = 16-row group, y = co-group (2 couts), z = b. block 256.
// Thread (ry = t>>4, xg = t&15): 4 px, 2 couts, q+k+v -> 24 accs.
// Weights: 108 floats/round staged via LDS (broadcast reads).
__global__ __launch_bounds__(256, 2) void convqkv_f32(
    const float* __restrict__ f1, const float* __restrict__ f2,
    const float* __restrict__ q_w, const float* __restrict__ q_b,
    const float* __restrict__ q_g, const float* __restrict__ q_be,
    const float* __restrict__ q_m, const float* __restrict__ q_va,
    const float* __restrict__ k_w, const float* __restrict__ k_b,
    const float* __restrict__ k_g, const float* __restrict__ k_be,
    const float* __restrict__ k_m, const float* __restrict__ k_va,
    const float* __restrict__ v_w, const float* __restrict__ v_b,
    const float* __restrict__ v_g, const float* __restrict__ v_be,
    const float* __restrict__ v_m, const float* __restrict__ v_va,
    float* __restrict__ qo, float* __restrict__ ko, float* __restrict__ vo)
{
  __shared__ float tA[2][CTSZ];  // f1 tiles (ci 2r, 2r+1)
  __shared__ float tB[2][CTSZ];  // f2 tiles
  __shared__ float wlds[112];    // 108 weights: [T][cc][s*9 + ky*3 + kx]

  const int b   = blockIdx.z;
  const int co0 = blockIdx.y * 2;
  const int y0  = blockIdx.x * 16;
  const int t   = threadIdx.x;
  const int ry  = t >> 4;        // output row within tile (0..15)
  const int xg  = t & 15;
  const int x0  = xg * 4;

  // BN fold: r = acc*scale + shift
  float qs[2], qsh[2], ks[2], ksh[2], vs[2], vsh[2];
  #pragma unroll
  for (int cc = 0; cc < 2; ++cc) {
    const int c = co0 + cc;
    float iv;
    iv = q_g[c] * rsqrtf(q_va[c] + 1e-5f);
    qs[cc] = iv; qsh[cc] = q_b[c] * iv + q_be[c] - q_m[c] * iv;
    iv = k_g[c] * rsqrtf(k_va[c] + 1e-5f);
    ks[cc] = iv; ksh[cc] = k_b[c] * iv + k_be[c] - k_m[c] * iv;
    iv = v_g[c] * rsqrtf(v_va[c] + 1e-5f);
    vs[cc] = iv; vsh[cc] = v_b[c] * iv + v_be[c] - v_m[c] * iv;
  }

  const float* srcA = f1 + (size_t)b * 256 * 4096;
  const float* srcB = f2 + (size_t)b * 256 * 4096;

  float4 rA[2][2], rB[2][2];
  const int row0 = t >> 4;          // pass-0 row (0..15)
  const int row1 = 16 + (t >> 4);   // pass-1 row (16..17), only t<32
  const int grp  = t & 15;

  const int wseg = t / 18;
  const int wkk  = t - wseg * 18;
  const float* wptr = (wseg < 2) ? q_w : ((wseg < 4) ? k_w : v_w);
  const int wbase0 = (co0 + (wseg & 1)) * 256 * 9 + wkk;
  float wreg = 0.f;

  #define LOADREGS(R)                                                         \
    {                                                                         \
      _Pragma("unroll")                                                       \
      for (int s = 0; s < 2; ++s) {                                           \
        const size_t cb = (size_t)((R) * 2 + s) * 4096;                       \
        {                                                                     \
          const int gy = y0 - 1 + row0;                                       \
          float4 a = make_float4(0.f, 0.f, 0.f, 0.f);                         \
          float4 bb = make_float4(0.f, 0.f, 0.f, 0.f);                        \
          if (gy >= 0 && gy <= 63) {                                          \
            a  = *(const float4*)(srcA + cb + gy * 64 + grp * 4);             \
            bb = *(const float4*)(srcB + cb + gy * 64 + grp * 4);             \
          }                                                                   \
          rA[s][0] = a; rB[s][0] = bb;                                        \
        }                                                                     \
        if (t < 32) {                                                         \
          const int gy = y0 - 1 + row1;                                       \
          float4 a = make_float4(0.f, 0.f, 0.f, 0.f);                         \
          float4 bb = make_float4(0.f, 0.f, 0.f, 0.f);                        \
          if (gy >= 0 && gy <= 63) {                                          \
            a  = *(const float4*)(srcA + cb + gy * 64 + grp * 4);             \
            bb = *(const float4*)(srcB + cb + gy * 64 + grp * 4);             \
          }                                                                   \
          rA[s][1] = a; rB[s][1] = bb;                                        \
        }                                                                     \
      }                                                                       \
      if (t < 108) wreg = wptr[wbase0 + (R) * 18];                            \
    }

  float accQ[2][4] = {{0.f}}, accK[2][4] = {{0.f}}, accV[2][4] = {{0.f}};

  LOADREGS(0);

  for (int r = 0; r < 128; ++r) {
    __syncthreads();  // prior round's LDS reads complete
    #pragma unroll
    for (int s = 0; s < 2; ++s) {
      *(float4*)(&tA[s][row0 * CTSTR + grp * 4]) = rA[s][0];
      *(float4*)(&tB[s][row0 * CTSTR + grp * 4]) = rB[s][0];
      if (t < 32) {
        *(float4*)(&tA[s][row1 * CTSTR + grp * 4]) = rA[s][1];
        *(float4*)(&tB[s][row1 * CTSTR + grp * 4]) = rB[s][1];
      }
    }
    if (t < 108) wlds[t] = wreg;
    __syncthreads();  // tiles + weights ready
    if (r < 127) LOADREGS(r + 1);  // prefetch in flight under FMA phase

    #pragma unroll
    for (int s = 0; s < 2; ++s) {
      #pragma unroll
      for (int ky = 0; ky < 3; ++ky) {
        const float4 a4 = *(const float4*)(&tA[s][(ry + ky) * CTSTR + x0]);
        const float4 b4 = *(const float4*)(&tB[s][(ry + ky) * CTSTR + x0]);
        const float ca[6] = {dpp_left(a4.w), a4.x, a4.y, a4.z, a4.w, dpp_right(a4.x)};
        const float cb[6] = {dpp_left(b4.w), b4.x, b4.y, b4.z, b4.w, dpp_right(b4.x)};
        #pragma unroll
        for (int cc = 0; cc < 2; ++cc) {
          const int wb = cc * 18 + s * 9 + ky * 3;
          const float q0 = wlds[wb],      q1 = wlds[wb + 1],      q2 = wlds[wb + 2];
          const float k0 = wlds[36 + wb], k1 = wlds[36 + wb + 1], k2 = wlds[36 + wb + 2];
          const float v0 = wlds[72 + wb], v1 = wlds[72 + wb + 1], v2 = wlds[72 + wb + 2];
          #pragma unroll
          for (int px = 0; px < 4; ++px) {
            accQ[cc][px] += cb[px] * q0 + cb[px + 1] * q1 + cb[px + 2] * q2;
            accK[cc][px] += ca[px] * k0 + ca[px + 1] * k1 + ca[px + 2] * k2;
            accV[cc][px] += ca[px] * v0 + ca[px + 1] * v1 + ca[px + 2] * v2;
          }
        }
      }
    }
  }

  // epilogue: BN + ReLU, float4 stores
  const size_t ob = ((size_t)b * 64 + co0) * 4096 + (size_t)(y0 + ry) * 64 + x0;
  #pragma unroll
  for (int cc = 0; cc < 2; ++cc) {
    float4 o;
    o.x = fmaxf(accQ[cc][0] * qs[cc] + qsh[cc], 0.f);
    o.y = fmaxf(accQ[cc][1] * qs[cc] + qsh[cc], 0.f);
    o.z = fmaxf(accQ[cc][2] * qs[cc] + qsh[cc], 0.f);
    o.w = fmaxf(accQ[cc][3] * qs[cc] + qsh[cc], 0.f);
    *(float4*)(qo + ob + (size_t)cc * 4096) = o;
    o.x = fmaxf(accK[cc][0] * ks[cc] + ksh[cc], 0.f);
    o.y = fmaxf(accK[cc][1] * ks[cc] + ksh[cc], 0.f);
    o.z = fmaxf(accK[cc][2] * ks[cc] + ksh[cc], 0.f);
    o.w = fmaxf(accK[cc][3] * ks[cc] + ksh[cc], 0.f);
    *(float4*)(ko + ob + (size_t)cc * 4096) = o;
    o.x = fmaxf(accV[cc][0] * vs[cc] + vsh[cc], 0.f);
    o.y = fmaxf(accV[cc][1] * vs[cc] + vsh[cc], 0.f);
    o.z = fmaxf(accV[cc][2] * vs[cc] + vsh[cc], 0.f);
    o.w = fmaxf(accV[cc][3] * vs[cc] + vsh[cc], 0.f);
    *(float4*)(vo + ob + (size_t)cc * 4096) = o;
  }
}

// ---------------------------------------------------------------------------
// Flash-style attention, fp32 (unchanged from R18).
__global__ __launch_bounds__(256) void attention_flash_f32(
    const float* __restrict__ q, const float* __restrict__ k,
    const float* __restrict__ v, float* __restrict__ f)
{
  __shared__ float kp_lds[64 * 68];
  __shared__ float vt_lds[64 * 68];
  __shared__ float qt_lds[64 * 68];

  const int lin = blockIdx.x;
  const int b = (lin & 7) >> 1;
  const int nb = ((lin >> 3) << 1) | (lin & 1);
  const int n0 = nb * 64;

  const int t = threadIdx.x;
  const int mg = t & 15;
  const int ng = t >> 4;

  const float* qb = q + (size_t)b * 64 * 4096;
  const float* kb = k + (size_t)b * 64 * 4096;
  const float* vb = v + (size_t)b * 64 * 4096;

  {
    const int nn = t & 15;
    const int c0 = t >> 4;
    #pragma unroll
    for (int p = 0; p < 4; ++p) {
      const int c = c0 + p * 16;
      const float4 val = *(const float4*)(qb + (size_t)c * 4096 + n0 + nn * 4);
      *(float4*)(qt_lds + c * 68 + nn * 4) = val;
    }
  }

  float acc[4][4] = {{0.f}};
  float m_run[4], l_run[4];
  #pragma unroll
  for (int i = 0; i < 4; ++i) { m_run[i] = -1e30f; l_run[i] = 0.f; }

  const int kc  = t >> 2;
  const int kf  = t & 3;
  const int vm4 = t & 15;
  const int vc0 = t >> 4;

  float4 kreg[4], vreg[4];
  #pragma unroll
  for (int r = 0; r < 4; ++r)
    kreg[r] = *(const float4*)(kb + (size_t)kc * 4096 + (kf + 4 * r) * 4);
  #pragma unroll
  for (int p = 0; p < 4; ++p)
    vreg[p] = *(const float4*)(vb + (size_t)(vc0 + 16 * p) * 4096 + vm4 * 4);

  for (int tile = 0; tile < 64; ++tile) {
    __syncthreads();

    #pragma unroll
    for (int r = 0; r < 4; ++r)
      *(float4*)(kp_lds + kc * 68 + (kf + 4 * r) * 4) = kreg[r];
    #pragma unroll
    for (int p = 0; p < 4; ++p) {
      const float4 vv = vreg[p];
      const int c = vc0 + 16 * p;
      vt_lds[(vm4 * 4 + 0) * 68 + c] = vv.x;
      vt_lds[(vm4 * 4 + 1) * 68 + c] = vv.y;
      vt_lds[(vm4 * 4 + 2) * 68 + c] = vv.z;
      vt_lds[(vm4 * 4 + 3) * 68 + c] = vv.w;
    }
    __syncthreads();
    if (tile < 63) {
      const int m0 = (tile + 1) * 64;
      #pragma unroll
      for (int r = 0; r < 4; ++r)
        kreg[r] = *(const float4*)(kb + (size_t)kc * 4096 + m0 + (kf + 4 * r) * 4);
      #pragma unroll
      for (int p = 0; p < 4; ++p)
        vreg[p] = *(const float4*)(vb + (size_t)(vc0 + 16 * p) * 4096 + m0 + vm4 * 4);
    }

    float s[4][4] = {{0.f}};
    #pragma unroll 8
    for (int c = 0; c < 64; ++c) {
      const float4 q4 = *(const float4*)(qt_lds + c * 68 + 4 * ng);
      const float4 k4 = *(const float4*)(kp_lds + c * 68 + 4 * mg);
      const float qa[4] = {q4.x, q4.y, q4.z, q4.w};
      const float ka[4] = {k4.x, k4.y, k4.z, k4.w};
      #pragma unroll
      for (int i = 0; i < 4; ++i)
        #pragma unroll
        for (int j = 0; j < 4; ++j)
          s[i][j] += qa[i] * ka[j];
    }

    #pragma unroll
    for (int i = 0; i < 4; ++i) {
      float rm = fmaxf(fmaxf(s[i][0], s[i][1]), fmaxf(s[i][2], s[i][3]));
      rm = fmaxf(rm, __shfl_xor(rm, 1));
      rm = fmaxf(rm, __shfl_xor(rm, 2));
      rm = fmaxf(rm, __shfl_xor(rm, 4));
      rm = fmaxf(rm, __shfl_xor(rm, 8));
      const float mn = fmaxf(m_run[i], rm);
      const float al = __expf(m_run[i] - mn);
      m_run[i] = mn;
      float rs = 0.f;
      #pragma unroll
      for (int j = 0; j < 4; ++j) { s[i][j] = __expf(s[i][j] - mn); rs += s[i][j]; }
      rs += __shfl_xor(rs, 1);
      rs += __shfl_xor(rs, 2);
      rs += __shfl_xor(rs, 4);
      rs += __shfl_xor(rs, 8);
      l_run[i] = al * l_run[i] + rs;
      #pragma unroll
      for (int j = 0; j < 4; ++j) acc[i][j] *= al;
    }

    __syncthreads();
    #pragma unroll
    for (int i = 0; i < 4; ++i)
      *(float4*)(kp_lds + (4 * ng + i) * 68 + 4 * mg) =
          make_float4(s[i][0], s[i][1], s[i][2], s[i][3]);
    __syncthreads();

    #pragma unroll 4
    for (int m4 = 0; m4 < 16; ++m4) {
      float pa[4][4], va[4][4];
      #pragma unroll
      for (int i = 0; i < 4; ++i) {
        const float4 p4 = *(const float4*)(kp_lds + (4 * ng + i) * 68 + m4 * 4);
        pa[i][0] = p4.x; pa[i][1] = p4.y; pa[i][2] = p4.z; pa[i][3] = p4.w;
      }
      #pragma unroll
      for (int jm = 0; jm < 4; ++jm) {
        const float4 v4 = *(const float4*)(vt_lds + (m4 * 4 + jm) * 68 + 4 * mg);
        va[jm][0] = v4.x; va[jm][1] = v4.y; va[jm][2] = v4.z; va[jm][3] = v4.w;
      }
      #pragma unroll
      for (int i = 0; i < 4; ++i)
        #pragma unroll
        for (int jm = 0; jm < 4; ++jm)
          #pragma unroll
          for (int j = 0; j < 4; ++j)
            acc[i][j] += pa[i][jm] * va[jm][j];
    }
  }

  __syncthreads();
  #pragma unroll
  for (int i = 0; i < 4; ++i) {
    const float inv = 1.f / l_run[i];
    #pragma unroll
    for (int j = 0; j < 4; ++j)
      qt_lds[(4 * mg + j) * 68 + 4 * ng + i] = acc[i][j] * inv;
  }
  __syncthreads();
  {
    const int c = t >> 2;
    #pragma unroll
    for (int r = 0; r < 4; ++r) {
      const int f4i = (t & 3) + 4 * r;
      *(float4*)(f + ((size_t)b * 64 + c) * 4096 + n0 + f4i * 4) =
          *(const float4*)(qt_lds + c * 68 + f4i * 4);
    }
  }
}

// ---------------------------------------------------------------------------
// conv_r: conv3x3 + BN + ReLU + residual.  Cin=64 -> Cout=256.  fp32.
// grid (4, 64, 4) = 1024 blocks (4/CU). DPP halo, aligned b128 reads only.
__global__ __launch_bounds__(256, 4) void conv_r_f32(
    const float* __restrict__ fin, const float* __restrict__ w,
    const float* __restrict__ bi, const float* __restrict__ g,
    const float* __restrict__ be, const float* __restrict__ mu,
    const float* __restrict__ va, const float* __restrict__ res,
    float* __restrict__ out)
{
  __shared__ float tA[2][CTSZ];
  __shared__ float wlds[80];   // 72 weights: [cc][s*9 + ky*3 + kx]

  const int b   = blockIdx.z;
  const int co0 = blockIdx.y * 4;
  const int y0  = blockIdx.x * 16;
  const int t   = threadIdx.x;
  const int ry  = t >> 4;
  const int xg  = t & 15;
  const int x0  = xg * 4;

  float sc[4], sh[4];
  #pragma unroll
  for (int cc = 0; cc < 4; ++cc) {
    const int c = co0 + cc;
    const float iv = g[c] * rsqrtf(va[c] + 1e-5f);
    sc[cc] = iv; sh[cc] = bi[c] * iv + be[c] - mu[c] * iv;
  }

  const float* srcA = fin + (size_t)b * 64 * 4096;
  float4 rA[2][2];
  const int row0 = t >> 4;
  const int row1 = 16 + (t >> 4);
  const int grp  = t & 15;

  const int wseg = t / 18;
  const int wkk  = t - wseg * 18;
  const int wbase0 = (co0 + wseg) * 64 * 9 + wkk;
  float wreg = 0.f;

  #define LOADR(R)                                                            \
    {                                                                         \
      _Pragma("unroll")                                                       \
      for (int s = 0; s < 2; ++s) {                                           \
        const size_t cb = (size_t)((R) * 2 + s) * 4096;                       \
        {                                                                     \
          const int gy = y0 - 1 + row0;                                       \
          float4 a = make_float4(0.f, 0.f, 0.f, 0.f);                         \
          if (gy >= 0 && gy <= 63)                                            \
            a = *(const float4*)(srcA + cb + gy * 64 + grp * 4);              \
          rA[s][0] = a;                                                       \
        }                                                                     \
        if (t < 32) {                                                         \
          const int gy = y0 - 1 + row1;                                       \
          float4 a = make_float4(0.f, 0.f, 0.f, 0.f);                         \
          if (gy >= 0 && gy <= 63)                                            \
            a = *(const float4*)(srcA + cb + gy * 64 + grp * 4);              \
          rA[s][1] = a;                                                       \
        }                                                                     \
      }                                                                       \
      if (t < 72) wreg = w[wbase0 + (R) * 18];                                \
    }

  float acc[4][4] = {{0.f}};
  LOADR(0);

  for (int r = 0; r < 32; ++r) {
    __syncthreads();
    #pragma unroll
    for (int s = 0; s < 2; ++s) {
      *(float4*)(&tA[s][row0 * CTSTR + grp * 4]) = rA[s][0];
      if (t < 32)
        *(float4*)(&tA[s][row1 * CTSTR + grp * 4]) = rA[s][1];
    }
    if (t < 72) wlds[t] = wreg;
    __syncthreads();
    if (r < 31) LOADR(r + 1);

    #pragma unroll
    for (int s = 0; s < 2; ++s) {
      #pragma unroll
      for (int ky = 0; ky < 3; ++ky) {
        const float4 a4 = *(const float4*)(&tA[s][(ry + ky) * CTSTR + x0]);
        const float ca[6] = {dpp_left(a4.w), a4.x, a4.y, a4.z, a4.w, dpp_right(a4.x)};
        #pragma unroll
        for (int cc = 0; cc < 4; ++cc) {
          const int wb = cc * 18 + s * 9 + ky * 3;
          const float w0 = wlds[wb], w1 = wlds[wb + 1], w2 = wlds[wb + 2];
          #pragma unroll
          for (int px = 0; px < 4; ++px)
            acc[cc][px] += ca[px] * w0 + ca[px + 1] * w1 + ca[px + 2] * w2;
        }
      }
    }
  }

  const size_t ob = ((size_t)b * 256 + co0) * 4096 + (size_t)(y0 + ry) * 64 + x0;
  #pragma unroll
  for (int cc = 0; cc < 4; ++cc) {
    const float4 rv = *(const float4*)(res + ob + (size_t)cc * 4096);
    float4 o;
    o.x = rv.x + fmaxf(acc[cc][0] * sc[cc] + sh[cc], 0.f);
    o.y = rv.y + fmaxf(acc[cc][1] * sc[cc] + sh[cc], 0.f);
    o.z = rv.z + fmaxf(acc[cc][2] * sc[cc] + sh[cc], 0.f);
    o.w = rv.w + fmaxf(acc[cc][3] * sc[cc] + sh[cc], 0.f);
    *(float4*)(out + ob + (size_t)cc * 4096) = o;
  }
}

// ---------------------------------------------------------------------------
extern "C" void kernel_launch(void* const* d_in, const int* in_sizes, int n_in,
                              void* d_out, int out_size, void* d_ws, size_t ws_size,
                              hipStream_t stream) {
  const float* f1 = (const float*)d_in[0];
  const float* f2 = (const float*)d_in[1];
  const float* qw = (const float*)d_in[2];  const float* qb = (const float*)d_in[3];
  const float* qg = (const float*)d_in[4];  const float* qbe = (const float*)d_in[5];
  const float* qm = (const float*)d_in[6];  const float* qv = (const float*)d_in[7];
  const float* kw = (const float*)d_in[8];  const float* kb = (const float*)d_in[9];
  const float* kg = (const float*)d_in[10]; const float* kbe = (const float*)d_in[11];
  const float* km = (const float*)d_in[12]; const float* kv = (const float*)d_in[13];
  const float* vw = (const float*)d_in[14]; const float* vb = (const float*)d_in[15];
  const float* vg = (const float*)d_in[16]; const float* vbe = (const float*)d_in[17];
  const float* vm = (const float*)d_in[18]; const float* vv = (const float*)d_in[19];
  const float* rw = (const float*)d_in[20]; const float* rb = (const float*)d_in[21];
  const float* rg = (const float*)d_in[22]; const float* rbe = (const float*)d_in[23];
  const float* rm = (const float*)d_in[24]; const float* rv = (const float*)d_in[25];

  hipStreamCaptureStatus cap = hipStreamCaptureStatusNone;
  unsigned long long capid = 0;
  const hipError_t ce = hipStreamGetCaptureInfo(stream, &cap, &capid);
  const bool capturing = (ce == hipSuccess) && (cap != hipStreamCaptureStatusNone);

  // Workspace: q,k,v,f fp32 [4][64][4096] = 4 MB each (ws_size = 256 MB).
  const size_t SZ1 = (size_t)4 * 64 * 4096 * 4;
  float* qp = (float*)d_ws;
  float* kp = (float*)((char*)d_ws + SZ1);
  float* vp = (float*)((char*)d_ws + 2 * SZ1);
  float* fp = (float*)((char*)d_ws + 3 * SZ1);

  convqkv_f32<<<dim3(4, 32, 4), 256, 0, stream>>>(
      f1, f2,
      qw, qb, qg, qbe, qm, qv,
      kw, kb, kg, kbe, km, kv,
      vw, vb, vg, vbe, vm, vv,
      qp, kp, vp);
  attention_flash_f32<<<dim3(256), 256, 0, stream>>>(qp, kp, vp, fp);
  conv_r_f32<<<dim3(4, 64, 4), 256, 0, stream>>>(fp, rw, rb, rg, rbe, rm, rv,
                                                 f1, (float*)d_out);

  if (!capturing) {
    const hipError_t le = hipGetLastError();
    const hipError_t se = hipStreamSynchronize(stream);
    float h[4] = {0, 0, 0, 0};
    (void)hipMemcpy(h, d_out, 16, hipMemcpyDeviceToHost);
    fprintf(stderr,
        "ATHENA_R19 dpp-halo le=%d sync=%d out=[%g %g %g %g]\n",
        (int)le, (int)se, h[0], h[1], h[2], h[3]);
    fflush(stderr);
  }
}

// Round 6
// 906.089 us; speedup vs baseline: 5.7334x; 1.0141x over previous
//
#include <hip/hip_runtime.h>
#include <cstdio>

// ============================================================================
// ROUND 20: attention occupancy fix.
// R19 counters: attention 470us is now the top dispatch. VALUBusy 38%,
// Occupancy 11.5% (grid 256 = 1 block/CU, 4 waves lockstep through 4
// barriers/tile -> all staging+LDS+barrier stalls exposed). FMA issue floor
// is 109us -> stall-bound, not pipe-bound.
// Fix: 32 queries/block -> 512 blocks = 2 independent blocks/CU; LDS 52->44KB
// (Q stride 36); thread tile 2n x 4m. Accumulation order bitwise identical.
// Convs unchanged from R19.
// ============================================================================

// Keeps the harness-stub identifier name (unused utility).
__global__ __launch_bounds__(256) void CrossModalityPositionAttention_56556129354448_kernel(
    float* dst, float val, int n)
{
  const int i = blockIdx.x * 256 + threadIdx.x;
  if (i < n) dst[i] = val;
}

// ---------------------------------------------------------------------------
// DPP lane-shift helpers (conv halo).
__device__ __forceinline__ float dpp_left(float x) {
  return __int_as_float(__builtin_amdgcn_update_dpp(
      0, __float_as_int(x), 0x111, 0xF, 0xF, true));   // row_shr:1
}
__device__ __forceinline__ float dpp_right(float x) {
  return __int_as_float(__builtin_amdgcn_update_dpp(
      0, __float_as_int(x), 0x101, 0xF, 0xF, true));   // row_shl:1
}

#define CTROWS 18
#define CTSTR  64
#define CTSZ   (CTROWS * CTSTR)   // 1152 floats

// ---------------------------------------------------------------------------
// Fused q/k/v conv3x3 + BN + ReLU (unchanged from R19).
__global__ __launch_bounds__(256, 2) void convqkv_f32(
    const float* __restrict__ f1, const float* __restrict__ f2,
    const float* __restrict__ q_w, const float* __restrict__ q_b,
    const float* __restrict__ q_g, const float* __restrict__ q_be,
    const float* __restrict__ q_m, const float* __restrict__ q_va,
    const float* __restrict__ k_w, const float* __restrict__ k_b,
    const float* __restrict__ k_g, const float* __restrict__ k_be,
    const float* __restrict__ k_m, const float* __restrict__ k_va,
    const float* __restrict__ v_w, const float* __restrict__ v_b,
    const float* __restrict__ v_g, const float* __restrict__ v_be,
    const float* __restrict__ v_m, const float* __restrict__ v_va,
    float* __restrict__ qo, float* __restrict__ ko, float* __restrict__ vo)
{
  __shared__ float tA[2][CTSZ];
  __shared__ float tB[2][CTSZ];
  __shared__ float wlds[112];

  const int b   = blockIdx.z;
  const int co0 = blockIdx.y * 2;
  const int y0  = blockIdx.x * 16;
  const int t   = threadIdx.x;
  const int ry  = t >> 4;
  const int xg  = t & 15;
  const int x0  = xg * 4;

  float qs[2], qsh[2], ks[2], ksh[2], vs[2], vsh[2];
  #pragma unroll
  for (int cc = 0; cc < 2; ++cc) {
    const int c = co0 + cc;
    float iv;
    iv = q_g[c] * rsqrtf(q_va[c] + 1e-5f);
    qs[cc] = iv; qsh[cc] = q_b[c] * iv + q_be[c] - q_m[c] * iv;
    iv = k_g[c] * rsqrtf(k_va[c] + 1e-5f);
    ks[cc] = iv; ksh[cc] = k_b[c] * iv + k_be[c] - k_m[c] * iv;
    iv = v_g[c] * rsqrtf(v_va[c] + 1e-5f);
    vs[cc] = iv; vsh[cc] = v_b[c] * iv + v_be[c] - v_m[c] * iv;
  }

  const float* srcA = f1 + (size_t)b * 256 * 4096;
  const float* srcB = f2 + (size_t)b * 256 * 4096;

  float4 rA[2][2], rB[2][2];
  const int row0 = t >> 4;
  const int row1 = 16 + (t >> 4);
  const int grp  = t & 15;

  const int wseg = t / 18;
  const int wkk  = t - wseg * 18;
  const float* wptr = (wseg < 2) ? q_w : ((wseg < 4) ? k_w : v_w);
  const int wbase0 = (co0 + (wseg & 1)) * 256 * 9 + wkk;
  float wreg = 0.f;

  #define LOADREGS(R)                                                         \
    {                                                                         \
      _Pragma("unroll")                                                       \
      for (int s = 0; s < 2; ++s) {                                           \
        const size_t cb = (size_t)((R) * 2 + s) * 4096;                       \
        {                                                                     \
          const int gy = y0 - 1 + row0;                                       \
          float4 a = make_float4(0.f, 0.f, 0.f, 0.f);                         \
          float4 bb = make_float4(0.f, 0.f, 0.f, 0.f);                        \
          if (gy >= 0 && gy <= 63) {                                          \
            a  = *(const float4*)(srcA + cb + gy * 64 + grp * 4);             \
            bb = *(const float4*)(srcB + cb + gy * 64 + grp * 4);             \
          }                                                                   \
          rA[s][0] = a; rB[s][0] = bb;                                        \
        }                                                                     \
        if (t < 32) {                                                         \
          const int gy = y0 - 1 + row1;                                       \
          float4 a = make_float4(0.f, 0.f, 0.f, 0.f);                         \
          float4 bb = make_float4(0.f, 0.f, 0.f, 0.f);                        \
          if (gy >= 0 && gy <= 63) {                                          \
            a  = *(const float4*)(srcA + cb + gy * 64 + grp * 4);             \
            bb = *(const float4*)(srcB + cb + gy * 64 + grp * 4);             \
          }                                                                   \
          rA[s][1] = a; rB[s][1] = bb;                                        \
        }                                                                     \
      }                                                                       \
      if (t < 108) wreg = wptr[wbase0 + (R) * 18];                            \
    }

  float accQ[2][4] = {{0.f}}, accK[2][4] = {{0.f}}, accV[2][4] = {{0.f}};

  LOADREGS(0);

  for (int r = 0; r < 128; ++r) {
    __syncthreads();
    #pragma unroll
    for (int s = 0; s < 2; ++s) {
      *(float4*)(&tA[s][row0 * CTSTR + grp * 4]) = rA[s][0];
      *(float4*)(&tB[s][row0 * CTSTR + grp * 4]) = rB[s][0];
      if (t < 32) {
        *(float4*)(&tA[s][row1 * CTSTR + grp * 4]) = rA[s][1];
        *(float4*)(&tB[s][row1 * CTSTR + grp * 4]) = rB[s][1];
      }
    }
    if (t < 108) wlds[t] = wreg;
    __syncthreads();
    if (r < 127) LOADREGS(r + 1);

    #pragma unroll
    for (int s = 0; s < 2; ++s) {
      #pragma unroll
      for (int ky = 0; ky < 3; ++ky) {
        const float4 a4 = *(const float4*)(&tA[s][(ry + ky) * CTSTR + x0]);
        const float4 b4 = *(const float4*)(&tB[s][(ry + ky) * CTSTR + x0]);
        const float ca[6] = {dpp_left(a4.w), a4.x, a4.y, a4.z, a4.w, dpp_right(a4.x)};
        const float cb[6] = {dpp_left(b4.w), b4.x, b4.y, b4.z, b4.w, dpp_right(b4.x)};
        #pragma unroll
        for (int cc = 0; cc < 2; ++cc) {
          const int wb = cc * 18 + s * 9 + ky * 3;
          const float q0 = wlds[wb],      q1 = wlds[wb + 1],      q2 = wlds[wb + 2];
          const float k0 = wlds[36 + wb], k1 = wlds[36 + wb + 1], k2 = wlds[36 + wb + 2];
          const float v0 = wlds[72 + wb], v1 = wlds[72 + wb + 1], v2 = wlds[72 + wb + 2];
          #pragma unroll
          for (int px = 0; px < 4; ++px) {
            accQ[cc][px] += cb[px] * q0 + cb[px + 1] * q1 + cb[px + 2] * q2;
            accK[cc][px] += ca[px] * k0 + ca[px + 1] * k1 + ca[px + 2] * k2;
            accV[cc][px] += ca[px] * v0 + ca[px + 1] * v1 + ca[px + 2] * v2;
          }
        }
      }
    }
  }

  const size_t ob = ((size_t)b * 64 + co0) * 4096 + (size_t)(y0 + ry) * 64 + x0;
  #pragma unroll
  for (int cc = 0; cc < 2; ++cc) {
    float4 o;
    o.x = fmaxf(accQ[cc][0] * qs[cc] + qsh[cc], 0.f);
    o.y = fmaxf(accQ[cc][1] * qs[cc] + qsh[cc], 0.f);
    o.z = fmaxf(accQ[cc][2] * qs[cc] + qsh[cc], 0.f);
    o.w = fmaxf(accQ[cc][3] * qs[cc] + qsh[cc], 0.f);
    *(float4*)(qo + ob + (size_t)cc * 4096) = o;
    o.x = fmaxf(accK[cc][0] * ks[cc] + ksh[cc], 0.f);
    o.y = fmaxf(accK[cc][1] * ks[cc] + ksh[cc], 0.f);
    o.z = fmaxf(accK[cc][2] * ks[cc] + ksh[cc], 0.f);
    o.w = fmaxf(accK[cc][3] * ks[cc] + ksh[cc], 0.f);
    *(float4*)(ko + ob + (size_t)cc * 4096) = o;
    o.x = fmaxf(accV[cc][0] * vs[cc] + vsh[cc], 0.f);
    o.y = fmaxf(accV[cc][1] * vs[cc] + vsh[cc], 0.f);
    o.z = fmaxf(accV[cc][2] * vs[cc] + vsh[cc], 0.f);
    o.w = fmaxf(accV[cc][3] * vs[cc] + vsh[cc], 0.f);
    *(float4*)(vo + ob + (size_t)cc * 4096) = o;
  }
}

// ---------------------------------------------------------------------------
// Flash attention, fp32.  32 queries/block, 512 blocks = 2 blocks/CU.
// Block decode: b = (lin&7)>>1 (XCD-pair -> one batch, K+V 2MB fits 4MB L2),
// nb = (lin>>3)*2 | (lin&1) in 0..127, n0 = 32*nb.
// Thread (ng = t>>4 in 0..15, mg = t&15): 2 n-rows (2ng+i), 4 m-cols (4mg+j).
// LDS 44KB: K [64][68] (reused as P[32][68]), V^T [64][68], Q [64][36].
__global__ __launch_bounds__(256, 2) void attention_flash_f32(
    const float* __restrict__ q, const float* __restrict__ k,
    const float* __restrict__ v, float* __restrict__ f)
{
  __shared__ float kp_lds[64 * 68];
  __shared__ float vt_lds[64 * 68];
  __shared__ float qt_lds[64 * 36];

  const int lin = blockIdx.x;
  const int b  = (lin & 7) >> 1;
  const int nb = ((lin >> 3) << 1) | (lin & 1);   // 0..127
  const int n0 = nb * 32;

  const int t = threadIdx.x;
  const int mg = t & 15;
  const int ng = t >> 4;    // 0..15

  const float* qb = q + (size_t)b * 64 * 4096;
  const float* kb = k + (size_t)b * 64 * 4096;
  const float* vb = v + (size_t)b * 64 * 4096;

  // ---- stage Q tile [c][n0..n0+31] into qt_lds[c][n], stride 36
  {
    const int nn = t & 7;      // float4 col index (0..7)
    const int c0 = t >> 3;     // 0..31
    #pragma unroll
    for (int p = 0; p < 2; ++p) {
      const int c = c0 + p * 32;
      const float4 val = *(const float4*)(qb + (size_t)c * 4096 + n0 + nn * 4);
      *(float4*)(qt_lds + c * 36 + nn * 4) = val;
    }
  }

  float acc[2][4] = {{0.f}};
  float m_run[2], l_run[2];
  #pragma unroll
  for (int i = 0; i < 2; ++i) { m_run[i] = -1e30f; l_run[i] = 0.f; }

  const int kc  = t >> 2;    // K row (0..63)
  const int kf  = t & 3;     // K float4 base
  const int vm4 = t & 15;    // V m-float4
  const int vc0 = t >> 4;    // V c base

  float4 kreg[4], vreg[4];
  #pragma unroll
  for (int r = 0; r < 4; ++r)
    kreg[r] = *(const float4*)(kb + (size_t)kc * 4096 + (kf + 4 * r) * 4);
  #pragma unroll
  for (int p = 0; p < 4; ++p)
    vreg[p] = *(const float4*)(vb + (size_t)(vc0 + 16 * p) * 4096 + vm4 * 4);

  for (int tile = 0; tile < 64; ++tile) {
    __syncthreads();

    #pragma unroll
    for (int r = 0; r < 4; ++r)
      *(float4*)(kp_lds + kc * 68 + (kf + 4 * r) * 4) = kreg[r];
    #pragma unroll
    for (int p = 0; p < 4; ++p) {
      const float4 vv = vreg[p];
      const int c = vc0 + 16 * p;
      vt_lds[(vm4 * 4 + 0) * 68 + c] = vv.x;
      vt_lds[(vm4 * 4 + 1) * 68 + c] = vv.y;
      vt_lds[(vm4 * 4 + 2) * 68 + c] = vv.z;
      vt_lds[(vm4 * 4 + 3) * 68 + c] = vv.w;
    }
    __syncthreads();
    if (tile < 63) {
      const int m0 = (tile + 1) * 64;
      #pragma unroll
      for (int r = 0; r < 4; ++r)
        kreg[r] = *(const float4*)(kb + (size_t)kc * 4096 + m0 + (kf + 4 * r) * 4);
      #pragma unroll
      for (int p = 0; p < 4; ++p)
        vreg[p] = *(const float4*)(vb + (size_t)(vc0 + 16 * p) * 4096 + m0 + vm4 * 4);
    }

    // ---- QK: s[i][j] = sum_c Q[c][2ng+i] * K[c][4mg+j]
    float s[2][4] = {{0.f}};
    #pragma unroll 8
    for (int c = 0; c < 64; ++c) {
      const float2 q2 = *(const float2*)(qt_lds + c * 36 + 2 * ng);
      const float4 k4 = *(const float4*)(kp_lds + c * 68 + 4 * mg);
      const float ka[4] = {k4.x, k4.y, k4.z, k4.w};
      #pragma unroll
      for (int j = 0; j < 4; ++j) {
        s[0][j] += q2.x * ka[j];
        s[1][j] += q2.y * ka[j];
      }
    }

    // ---- online softmax (per n-row, across 16 mg-lanes)
    #pragma unroll
    for (int i = 0; i < 2; ++i) {
      float rm = fmaxf(fmaxf(s[i][0], s[i][1]), fmaxf(s[i][2], s[i][3]));
      rm = fmaxf(rm, __shfl_xor(rm, 1));
      rm = fmaxf(rm, __shfl_xor(rm, 2));
      rm = fmaxf(rm, __shfl_xor(rm, 4));
      rm = fmaxf(rm, __shfl_xor(rm, 8));
      const float mn = fmaxf(m_run[i], rm);
      const float al = __expf(m_run[i] - mn);
      m_run[i] = mn;
      float rs = 0.f;
      #pragma unroll
      for (int j = 0; j < 4; ++j) { s[i][j] = __expf(s[i][j] - mn); rs += s[i][j]; }
      rs += __shfl_xor(rs, 1);
      rs += __shfl_xor(rs, 2);
      rs += __shfl_xor(rs, 4);
      rs += __shfl_xor(rs, 8);
      l_run[i] = al * l_run[i] + rs;
      #pragma unroll
      for (int j = 0; j < 4; ++j) acc[i][j] *= al;
    }

    __syncthreads();  // all K reads done before P overwrites kp_lds
    #pragma unroll
    for (int i = 0; i < 2; ++i)
      *(float4*)(kp_lds + (2 * ng + i) * 68 + 4 * mg) =
          make_float4(s[i][0], s[i][1], s[i][2], s[i][3]);
    __syncthreads();

    // ---- PV: acc[i][j] += sum_m P[2ng+i][m] * V[4mg+j][m]
    #pragma unroll 4
    for (int m4 = 0; m4 < 16; ++m4) {
      float pa[2][4], va[4][4];
      #pragma unroll
      for (int i = 0; i < 2; ++i) {
        const float4 p4 = *(const float4*)(kp_lds + (2 * ng + i) * 68 + m4 * 4);
        pa[i][0] = p4.x; pa[i][1] = p4.y; pa[i][2] = p4.z; pa[i][3] = p4.w;
      }
      #pragma unroll
      for (int jm = 0; jm < 4; ++jm) {
        const float4 v4 = *(const float4*)(vt_lds + (m4 * 4 + jm) * 68 + 4 * mg);
        va[jm][0] = v4.x; va[jm][1] = v4.y; va[jm][2] = v4.z; va[jm][3] = v4.w;
      }
      #pragma unroll
      for (int i = 0; i < 2; ++i)
        #pragma unroll
        for (int jm = 0; jm < 4; ++jm)
          #pragma unroll
          for (int j = 0; j < 4; ++j)
            acc[i][j] += pa[i][jm] * va[jm][j];
    }
  }

  // ---- epilogue: normalize, transpose through qt_lds, coalesced store
  __syncthreads();
  #pragma unroll
  for (int i = 0; i < 2; ++i) {
    const float inv = 1.f / l_run[i];
    #pragma unroll
    for (int j = 0; j < 4; ++j)
      qt_lds[(4 * mg + j) * 36 + 2 * ng + i] = acc[i][j] * inv;  // [c][n]
  }
  __syncthreads();
  {
    const int c = t >> 2;   // 0..63
    #pragma unroll
    for (int r = 0; r < 2; ++r) {
      const int f4i = (t & 3) + 4 * r;   // 0..7
      *(float4*)(f + ((size_t)b * 64 + c) * 4096 + n0 + f4i * 4) =
          *(const float4*)(qt_lds + c * 36 + f4i * 4);
    }
  }
}

// ---------------------------------------------------------------------------
// conv_r (unchanged from R19).
__global__ __launch_bounds__(256, 4) void conv_r_f32(
    const float* __restrict__ fin, const float* __restrict__ w,
    const float* __restrict__ bi, const float* __restrict__ g,
    const float* __restrict__ be, const float* __restrict__ mu,
    const float* __restrict__ va, const float* __restrict__ res,
    float* __restrict__ out)
{
  __shared__ float tA[2][CTSZ];
  __shared__ float wlds[80];

  const int b   = blockIdx.z;
  const int co0 = blockIdx.y * 4;
  const int y0  = blockIdx.x * 16;
  const int t   = threadIdx.x;
  const int ry  = t >> 4;
  const int xg  = t & 15;
  const int x0  = xg * 4;

  float sc[4], sh[4];
  #pragma unroll
  for (int cc = 0; cc < 4; ++cc) {
    const int c = co0 + cc;
    const float iv = g[c] * rsqrtf(va[c] + 1e-5f);
    sc[cc] = iv; sh[cc] = bi[c] * iv + be[c] - mu[c] * iv;
  }

  const float* srcA = fin + (size_t)b * 64 * 4096;
  float4 rA[2][2];
  const int row0 = t >> 4;
  const int row1 = 16 + (t >> 4);
  const int grp  = t & 15;

  const int wseg = t / 18;
  const int wkk  = t - wseg * 18;
  const int wbase0 = (co0 + wseg) * 64 * 9 + wkk;
  float wreg = 0.f;

  #define LOADR(R)                                                            \
    {                                                                         \
      _Pragma("unroll")                                                       \
      for (int s = 0; s < 2; ++s) {                                           \
        const size_t cb = (size_t)((R) * 2 + s) * 4096;                       \
        {                                                                     \
          const int gy = y0 - 1 + row0;                                       \
          float4 a = make_float4(0.f, 0.f, 0.f, 0.f);                         \
          if (gy >= 0 && gy <= 63)                                            \
            a = *(const float4*)(srcA + cb + gy * 64 + grp * 4);              \
          rA[s][0] = a;                                                       \
        }                                                                     \
        if (t < 32) {                                                         \
          const int gy = y0 - 1 + row1;                                       \
          float4 a = make_float4(0.f, 0.f, 0.f, 0.f);                         \
          if (gy >= 0 && gy <= 63)                                            \
            a = *(const float4*)(srcA + cb + gy * 64 + grp * 4);              \
          rA[s][1] = a;                                                       \
        }                                                                     \
      }                                                                       \
      if (t < 72) wreg = w[wbase0 + (R) * 18];                                \
    }

  float acc[4][4] = {{0.f}};
  LOADR(0);

  for (int r = 0; r < 32; ++r) {
    __syncthreads();
    #pragma unroll
    for (int s = 0; s < 2; ++s) {
      *(float4*)(&tA[s][row0 * CTSTR + grp * 4]) = rA[s][0];
      if (t < 32)
        *(float4*)(&tA[s][row1 * CTSTR + grp * 4]) = rA[s][1];
    }
    if (t < 72) wlds[t] = wreg;
    __syncthreads();
    if (r < 31) LOADR(r + 1);

    #pragma unroll
    for (int s = 0; s < 2; ++s) {
      #pragma unroll
      for (int ky = 0; ky < 3; ++ky) {
        const float4 a4 = *(const float4*)(&tA[s][(ry + ky) * CTSTR + x0]);
        const float ca[6] = {dpp_left(a4.w), a4.x, a4.y, a4.z, a4.w, dpp_right(a4.x)};
        #pragma unroll
        for (int cc = 0; cc < 4; ++cc) {
          const int wb = cc * 18 + s * 9 + ky * 3;
          const float w0 = wlds[wb], w1 = wlds[wb + 1], w2 = wlds[wb + 2];
          #pragma unroll
          for (int px = 0; px < 4; ++px)
            acc[cc][px] += ca[px] * w0 + ca[px + 1] * w1 + ca[px + 2] * w2;
        }
      }
    }
  }

  const size_t ob = ((size_t)b * 256 + co0) * 4096 + (size_t)(y0 + ry) * 64 + x0;
  #pragma unroll
  for (int cc = 0; cc < 4; ++cc) {
    const float4 rv = *(const float4*)(res + ob + (size_t)cc * 4096);
    float4 o;
    o.x = rv.x + fmaxf(acc[cc][0] * sc[cc] + sh[cc], 0.f);
    o.y = rv.y + fmaxf(acc[cc][1] * sc[cc] + sh[cc], 0.f);
    o.z = rv.z + fmaxf(acc[cc][2] * sc[cc] + sh[cc], 0.f);
    o.w = rv.w + fmaxf(acc[cc][3] * sc[cc] + sh[cc], 0.f);
    *(float4*)(out + ob + (size_t)cc * 4096) = o;
  }
}

// ---------------------------------------------------------------------------
extern "C" void kernel_launch(void* const* d_in, const int* in_sizes, int n_in,
                              void* d_out, int out_size, void* d_ws, size_t ws_size,
                              hipStream_t stream) {
  const float* f1 = (const float*)d_in[0];
  const float* f2 = (const float*)d_in[1];
  const float* qw = (const float*)d_in[2];  const float* qb = (const float*)d_in[3];
  const float* qg = (const float*)d_in[4];  const float* qbe = (const float*)d_in[5];
  const float* qm = (const float*)d_in[6];  const float* qv = (const float*)d_in[7];
  const float* kw = (const float*)d_in[8];  const float* kb = (const float*)d_in[9];
  const float* kg = (const float*)d_in[10]; const float* kbe = (const float*)d_in[11];
  const float* km = (const float*)d_in[12]; const float* kv = (const float*)d_in[13];
  const float* vw = (const float*)d_in[14]; const float* vb = (const float*)d_in[15];
  const float* vg = (const float*)d_in[16]; const float* vbe = (const float*)d_in[17];
  const float* vm = (const float*)d_in[18]; const float* vv = (const float*)d_in[19];
  const float* rw = (const float*)d_in[20]; const float* rb = (const float*)d_in[21];
  const float* rg = (const float*)d_in[22]; const float* rbe = (const float*)d_in[23];
  const float* rm = (const float*)d_in[24]; const float* rv = (const float*)d_in[25];

  hipStreamCaptureStatus cap = hipStreamCaptureStatusNone;
  unsigned long long capid = 0;
  const hipError_t ce = hipStreamGetCaptureInfo(stream, &cap, &capid);
  const bool capturing = (ce == hipSuccess) && (cap != hipStreamCaptureStatusNone);

  // Workspace: q,k,v,f fp32 [4][64][4096] = 4 MB each (ws_size = 256 MB).
  const size_t SZ1 = (size_t)4 * 64 * 4096 * 4;
  float* qp = (float*)d_ws;
  float* kp = (float*)((char*)d_ws + SZ1);
  float* vp = (float*)((char*)d_ws + 2 * SZ1);
  float* fp = (float*)((char*)d_ws + 3 * SZ1);

  convqkv_f32<<<dim3(4, 32, 4), 256, 0, stream>>>(
      f1, f2,
      qw, qb, qg, qbe, qm, qv,
      kw, kb, kg, kbe, km, kv,
      vw, vb, vg, vbe, vm, vv,
      qp, kp, vp);
  attention_flash_f32<<<dim3(512), 256, 0, stream>>>(qp, kp, vp, fp);
  conv_r_f32<<<dim3(4, 64, 4), 256, 0, stream>>>(fp, rw, rb, rg, rbe, rm, rv,
                                                 f1, (float*)d_out);

  if (!capturing) {
    const hipError_t le = hipGetLastError();
    const hipError_t se = hipStreamSynchronize(stream);
    float h[4] = {0, 0, 0, 0};
    (void)hipMemcpy(h, d_out, 16, hipMemcpyDeviceToHost);
    fprintf(stderr,
        "ATHENA_R20 attn-32q le=%d sync=%d out=[%g %g %g %g]\n",
        (int)le, (int)se, h[0], h[1], h[2], h[3]);
    fflush(stderr);
  }
}